// Round 2
// baseline (549.572 us; speedup 1.0000x reference)
//
#include <hip/hip_runtime.h>
#include <hip/hip_bf16.h>
#include <math.h>

#define T_SEQ 2048
#define BATCH 2
#define CDIM  2048
#define HQ    32
#define HKV   8
#define HD    64
#define GRP   4
#define NQKV  3072   // 2048 Q + 512 K + 512 V

typedef __attribute__((ext_vector_type(8))) short  bf16x8;
typedef __attribute__((ext_vector_type(8))) ushort u16x8;
typedef __attribute__((ext_vector_type(4))) float  f32x4;

static __device__ __forceinline__ float bf2f(ushort u) {
    union { unsigned int ui; float f; } v; v.ui = ((unsigned int)u) << 16; return v.f;
}
static __device__ __forceinline__ ushort f2bf(float f) {
    union { float f; unsigned int ui; } v; v.f = f;
    unsigned int r = v.ui + 0x7FFFu + ((v.ui >> 16) & 1u);
    return (ushort)(r >> 16);
}

// ---------------- fp32 -> bf16 convert (8 elems/thread) ----------------
__global__ void cvt_kernel(const float* __restrict__ in, ushort* __restrict__ out, long n) {
    long i = ((long)blockIdx.x * blockDim.x + threadIdx.x) * 8;
    if (i >= n) return;
    float4 a = *(const float4*)(in + i);
    float4 b = *(const float4*)(in + i + 4);
    u16x8 v;
    v[0] = f2bf(a.x); v[1] = f2bf(a.y); v[2] = f2bf(a.z); v[3] = f2bf(a.w);
    v[4] = f2bf(b.x); v[5] = f2bf(b.y); v[6] = f2bf(b.z); v[7] = f2bf(b.w);
    *(u16x8*)(out + i) = v;
}

// ---------------- bf16 GEMM: C[M,N] = A[M,K] * B[N,K]^T ----------------
// 128x128 tile, BK=64, 256 threads (4 waves, 2x2), global_load_lds staging.
template<bool F32OUT>
__global__ __launch_bounds__(256) void gemm_bt(const ushort* __restrict__ A,
                                               const ushort* __restrict__ B,
                                               void* __restrict__ C,
                                               int M, int N, int K) {
    __shared__ ushort As[128 * 64];
    __shared__ ushort Bs[128 * 64];
    const int tid  = threadIdx.x;
    const int wave = tid >> 6;
    const int lane = tid & 63;
    const int bm = blockIdx.x, bn = blockIdx.y;
    const int wm = wave >> 1, wn = wave & 1;

    f32x4 acc[4][4];
    #pragma unroll
    for (int i = 0; i < 4; ++i)
        #pragma unroll
        for (int j = 0; j < 4; ++j) { acc[i][j][0]=0.f; acc[i][j][1]=0.f; acc[i][j][2]=0.f; acc[i][j][3]=0.f; }

    const int r_sub  = tid >> 3;          // 0..31 : row within 32-row staging slab
    const int c_el   = (tid & 7) * 8;     // element col offset (8 bf16 = 16B)

    for (int k0 = 0; k0 < K; k0 += 64) {
        #pragma unroll
        for (int it = 0; it < 4; ++it) {
            int row = it * 32 + r_sub;
            const ushort* srcA = A + (size_t)(bm * 128 + row) * K + k0 + c_el;
            const ushort* srcB = B + (size_t)(bn * 128 + row) * K + k0 + c_el;
            __builtin_amdgcn_global_load_lds(
                (const __attribute__((address_space(1))) unsigned int*)srcA,
                (__attribute__((address_space(3))) unsigned int*)((char*)As + it * 4096 + wave * 1024),
                16, 0, 0);
            __builtin_amdgcn_global_load_lds(
                (const __attribute__((address_space(1))) unsigned int*)srcB,
                (__attribute__((address_space(3))) unsigned int*)((char*)Bs + it * 4096 + wave * 1024),
                16, 0, 0);
        }
        __syncthreads();

        const int lr = lane & 15;
        #pragma unroll
        for (int kk = 0; kk < 2; ++kk) {
            const int lk = kk * 32 + (lane >> 4) * 8;
            bf16x8 af[4], bfr[4];
            #pragma unroll
            for (int mi = 0; mi < 4; ++mi)
                af[mi] = *(const bf16x8*)&As[(wm * 64 + mi * 16 + lr) * 64 + lk];
            #pragma unroll
            for (int ni = 0; ni < 4; ++ni)
                bfr[ni] = *(const bf16x8*)&Bs[(wn * 64 + ni * 16 + lr) * 64 + lk];
            #pragma unroll
            for (int mi = 0; mi < 4; ++mi)
                #pragma unroll
                for (int ni = 0; ni < 4; ++ni)
                    acc[mi][ni] = __builtin_amdgcn_mfma_f32_16x16x32_bf16(af[mi], bfr[ni], acc[mi][ni], 0, 0, 0);
        }
        __syncthreads();
    }

    const int lr = lane & 15, lg = lane >> 4;
    #pragma unroll
    for (int mi = 0; mi < 4; ++mi)
        #pragma unroll
        for (int ni = 0; ni < 4; ++ni)
            #pragma unroll
            for (int r = 0; r < 4; ++r) {
                int row = bm * 128 + wm * 64 + mi * 16 + lg * 4 + r;
                int col = bn * 128 + wn * 64 + ni * 16 + lr;
                float v = acc[mi][ni][r];
                if (F32OUT) ((float*)C)[(size_t)row * N + col] = v;
                else        ((ushort*)C)[(size_t)row * N + col] = f2bf(v);
            }
}

// ---------------- RoPE + rearrange into per-head layouts ----------------
__global__ void rope_qk(const ushort* __restrict__ qkv, ushort* __restrict__ Qh, ushort* __restrict__ Kh) {
    const int NQP = BATCH * T_SEQ * HQ * (HD / 2);   // 4,194,304
    int i = blockIdx.x * blockDim.x + threadIdx.x;
    if (i < NQP) {
        int row = i >> 10;
        int idx = i & 1023;
        int h = idx >> 5, j = idx & 31;
        int t = row & (T_SEQ - 1), b = row >> 11;
        const ushort* src = qkv + (size_t)row * NQKV + h * HD + 2 * j;
        unsigned int pin = *(const unsigned int*)src;
        float xr = bf2f((ushort)(pin & 0xFFFF));
        float xi = bf2f((ushort)(pin >> 16));
        float ang = (float)t * exp2f((float)j * -0.4152410118609203f); // 10000^(-j/32)
        float c, s; sincosf(ang, &s, &c);
        float orr = xr * c - xi * s;
        float oi  = xr * s + xi * c;
        unsigned int pout = (unsigned int)f2bf(orr) | ((unsigned int)f2bf(oi) << 16);
        ushort* dst = Qh + ((size_t)((b * HQ + h) * T_SEQ + t)) * HD + 2 * j;
        *(unsigned int*)dst = pout;
    } else {
        int ii = i - NQP;             // K pairs: 1,048,576
        int row = ii >> 8;
        int idx = ii & 255;
        int hk = idx >> 5, j = idx & 31;
        int t = row & (T_SEQ - 1), b = row >> 11;
        const ushort* src = qkv + (size_t)row * NQKV + CDIM + hk * HD + 2 * j;
        unsigned int pin = *(const unsigned int*)src;
        float xr = bf2f((ushort)(pin & 0xFFFF));
        float xi = bf2f((ushort)(pin >> 16));
        float ang = (float)t * exp2f((float)j * -0.4152410118609203f);
        float c, s; sincosf(ang, &s, &c);
        float orr = xr * c - xi * s;
        float oi  = xr * s + xi * c;
        unsigned int pout = (unsigned int)f2bf(orr) | ((unsigned int)f2bf(oi) << 16);
        ushort* dst = Kh + ((size_t)((b * HKV + hk) * T_SEQ + t)) * HD + 2 * j;
        *(unsigned int*)dst = pout;
    }
}

// ---------------- V transpose: qkv V section -> Vt[(b*HKV+hk)*64+d][t] ----------------
__global__ __launch_bounds__(256) void v_transpose(const ushort* __restrict__ qkv, ushort* __restrict__ Vt) {
    __shared__ ushort Vs[64][80];     // pad to 80 elems -> break bank conflicts on transpose read
    int bh = blockIdx.x;              // b*HKV + hk, 0..15
    int tt = blockIdx.y;              // 0..31
    int b = bh >> 3, hk = bh & 7;
    int tid = threadIdx.x;
    #pragma unroll
    for (int c = 0; c < 2; ++c) {
        int rr = tid + c * 256;       // 0..511 -> full 64 rows x 64 cols
        int tl = rr >> 3, d0 = (rr & 7) * 8;
        int row = b * T_SEQ + tt * 64 + tl;
        u16x8 v = *(const u16x8*)(qkv + (size_t)row * NQKV + CDIM + HKV * HD + hk * HD + d0);
        *(u16x8*)&Vs[tl][d0] = v;
    }
    __syncthreads();
    #pragma unroll
    for (int c = 0; c < 2; ++c) {
        int ch = tid + c * 256;
        int d = ch >> 3, t8 = (ch & 7) * 8;
        u16x8 o;
        #pragma unroll
        for (int j = 0; j < 8; ++j) o[j] = Vs[t8 + j][d];
        *(u16x8*)(Vt + ((size_t)(bh * HD + d)) * T_SEQ + tt * 64 + t8) = o;
    }
}

// ---------------- Flash causal GQA attention ----------------
// grid: (T/64, HQ, B); 4 waves; wave w owns q rows [qb*64+w*16, +16)
__global__ __launch_bounds__(256) void attn_kernel(const ushort* __restrict__ Qh,
                                                   const ushort* __restrict__ Kh,
                                                   const ushort* __restrict__ Vt,
                                                   ushort* __restrict__ O) {
    __shared__ ushort Ks[64 * 64];
    __shared__ ushort Vs[64 * 64];
    __shared__ ushort Ps[4][16 * 64];
    const int qb = blockIdx.x, h = blockIdx.y, b = blockIdx.z;
    const int hk = h >> 2;
    const int tid = threadIdx.x, wave = tid >> 6, lane = tid & 63;
    const int lr = lane & 15, lg = lane >> 4;

    const ushort* Qbase = Qh + ((size_t)((b * HQ + h) * T_SEQ + qb * 64 + wave * 16 + lr)) * HD;
    bf16x8 qf[2];
    qf[0] = *(const bf16x8*)(Qbase + lg * 8);
    qf[1] = *(const bf16x8*)(Qbase + 32 + lg * 8);

    f32x4 oacc[4];
    #pragma unroll
    for (int dt = 0; dt < 4; ++dt) { oacc[dt][0]=0.f; oacc[dt][1]=0.f; oacc[dt][2]=0.f; oacc[dt][3]=0.f; }
    float m_r[4], l_r[4];
    #pragma unroll
    for (int r = 0; r < 4; ++r) { m_r[r] = -INFINITY; l_r[r] = 0.f; }

    const ushort* Kbase = Kh + (size_t)(b * HKV + hk) * T_SEQ * HD;
    const ushort* Vbase = Vt + (size_t)(b * HKV + hk) * HD * T_SEQ;
    const int srow = tid >> 3, scol = (tid & 7) * 8;    // srow 0..31
    const int qrow0 = qb * 64 + wave * 16 + lg * 4;
    const int nkt = qb + 1;

    for (int kt = 0; kt < nkt; ++kt) {
        const int t0 = kt * 64;
        // stage FULL 64x64 tiles: rows srow and srow+32
        #pragma unroll
        for (int half = 0; half < 2; ++half) {
            int r0 = srow + half * 32;
            *(u16x8*)&Ks[r0 * 64 + scol] = *(const u16x8*)(Kbase + (size_t)(t0 + r0) * HD + scol);
            *(u16x8*)&Vs[r0 * 64 + scol] = *(const u16x8*)(Vbase + (size_t)r0 * T_SEQ + t0 + scol);
        }
        __syncthreads();

        // S = Q K^T (scaled), 4 col-tiles of 16
        f32x4 sacc[4];
        #pragma unroll
        for (int ct = 0; ct < 4; ++ct) { sacc[ct][0]=0.f; sacc[ct][1]=0.f; sacc[ct][2]=0.f; sacc[ct][3]=0.f; }
        #pragma unroll
        for (int kk = 0; kk < 2; ++kk) {
            const int lk = kk * 32 + lg * 8;
            #pragma unroll
            for (int ct = 0; ct < 4; ++ct) {
                bf16x8 bf = *(const bf16x8*)&Ks[(ct * 16 + lr) * 64 + lk];
                sacc[ct] = __builtin_amdgcn_mfma_f32_16x16x32_bf16(qf[kk], bf, sacc[ct], 0, 0, 0);
            }
        }

        // mask + scale
        float sv[4][4];
        #pragma unroll
        for (int ct = 0; ct < 4; ++ct) {
            int colg = t0 + ct * 16 + lr;
            #pragma unroll
            for (int r = 0; r < 4; ++r) {
                float v = sacc[ct][r] * 0.125f;   // 1/sqrt(64)
                if (colg > qrow0 + r) v = -INFINITY;
                sv[ct][r] = v;
            }
        }

        // online softmax per row r (row owned by 16 lanes sharing lg)
        #pragma unroll
        for (int r = 0; r < 4; ++r) {
            float m = sv[0][r];
            m = fmaxf(m, sv[1][r]); m = fmaxf(m, sv[2][r]); m = fmaxf(m, sv[3][r]);
            m = fmaxf(m, __shfl_xor(m, 1));
            m = fmaxf(m, __shfl_xor(m, 2));
            m = fmaxf(m, __shfl_xor(m, 4));
            m = fmaxf(m, __shfl_xor(m, 8));
            float mn = fmaxf(m_r[r], m);
            float alpha = __expf(m_r[r] - mn);
            m_r[r] = mn;
            float lsum = 0.f;
            #pragma unroll
            for (int ct = 0; ct < 4; ++ct) {
                float p = __expf(sv[ct][r] - mn);
                sv[ct][r] = p;
                lsum += p;
            }
            lsum += __shfl_xor(lsum, 1);
            lsum += __shfl_xor(lsum, 2);
            lsum += __shfl_xor(lsum, 4);
            lsum += __shfl_xor(lsum, 8);
            l_r[r] = l_r[r] * alpha + lsum;
            #pragma unroll
            for (int dt = 0; dt < 4; ++dt) oacc[dt][r] *= alpha;
            #pragma unroll
            for (int ct = 0; ct < 4; ++ct)
                Ps[wave][(lg * 4 + r) * 64 + ct * 16 + lr] = f2bf(sv[ct][r]);
        }

        // O += P V
        #pragma unroll
        for (int kk = 0; kk < 2; ++kk) {
            const int lk = kk * 32 + lg * 8;
            bf16x8 pf = *(const bf16x8*)&Ps[wave][lr * 64 + lk];
            #pragma unroll
            for (int dt = 0; dt < 4; ++dt) {
                bf16x8 vf = *(const bf16x8*)&Vs[(dt * 16 + lr) * 64 + lk];
                oacc[dt] = __builtin_amdgcn_mfma_f32_16x16x32_bf16(pf, vf, oacc[dt], 0, 0, 0);
            }
        }
        __syncthreads();
    }

    // normalize + write attOut (bf16, [b*T+t, h*64+d])
    #pragma unroll
    for (int dt = 0; dt < 4; ++dt)
        #pragma unroll
        for (int r = 0; r < 4; ++r) {
            int t = qb * 64 + wave * 16 + lg * 4 + r;
            int d = dt * 16 + lr;
            float v = oacc[dt][r] / l_r[r];
            O[((size_t)(b * T_SEQ + t)) * CDIM + h * HD + d] = f2bf(v);
        }
}

extern "C" void kernel_launch(void* const* d_in, const int* in_sizes, int n_in,
                              void* d_out, int out_size, void* d_ws, size_t ws_size,
                              hipStream_t stream) {
    const float* x  = (const float*)d_in[0];
    const float* Wq = (const float*)d_in[1];
    const float* Wk = (const float*)d_in[2];
    const float* Wv = (const float*)d_in[3];
    const float* Wo = (const float*)d_in[4];
    float* out = (float*)d_out;

    // workspace layout (elements of ushort/bf16)
    ushort* xb    = (ushort*)d_ws;                 //  8,388,608  (x bf16)  [reused as attOut]
    ushort* wqkvb = xb    + 8388608;               //  6,291,456  (Wq|Wk|Wv bf16)
    ushort* wob   = wqkvb + 6291456;               //  4,194,304  (Wo bf16)
    ushort* qkv   = wob   + 4194304;               // 12,582,912  (QKV bf16, ld 3072)
    ushort* Qh    = qkv   + 12582912;              //  8,388,608
    ushort* Kh    = Qh    + 8388608;               //  2,097,152
    ushort* Vt    = Kh    + 2097152;               //  2,097,152
    ushort* attO  = xb;                            // alias: xb dead after QKV GEMM

    // 1) converts
    cvt_kernel<<<4096, 256, 0, stream>>>(x,  xb,    8388608);
    cvt_kernel<<<2048, 256, 0, stream>>>(Wq, wqkvb, 4194304);
    cvt_kernel<<< 512, 256, 0, stream>>>(Wk, wqkvb + 4194304, 1048576);
    cvt_kernel<<< 512, 256, 0, stream>>>(Wv, wqkvb + 5242880, 1048576);
    cvt_kernel<<<2048, 256, 0, stream>>>(Wo, wob,   4194304);

    // 2) fused QKV projection: qkv[4096,3072] = xb[4096,2048] @ wqkvb^T
    gemm_bt<false><<<dim3(32, 24), 256, 0, stream>>>(xb, wqkvb, qkv, 4096, 3072, 2048);

    // 3) RoPE + rearrange
    rope_qk<<<20480, 256, 0, stream>>>(qkv, Qh, Kh);
    v_transpose<<<dim3(16, 32), 256, 0, stream>>>(qkv, Vt);

    // 4) attention
    attn_kernel<<<dim3(32, 32, 2), 256, 0, stream>>>(Qh, Kh, Vt, attO);

    // 5) output projection: out[4096,2048] = attO @ wob^T (fp32 out)
    gemm_bt<true><<<dim3(32, 16), 256, 0, stream>>>(attO, wob, out, 4096, 2048, 2048);
}

// Round 3
// 409.990 us; speedup vs baseline: 1.3405x; 1.3405x over previous
//
#include <hip/hip_runtime.h>
#include <hip/hip_bf16.h>
#include <math.h>

#define T_SEQ 2048
#define BATCH 2
#define CDIM  2048
#define HQ    32
#define HKV   8
#define HD    64
#define GRP   4
#define NQKV  3072   // 2048 Q + 512 K + 512 V

typedef __attribute__((ext_vector_type(8))) short  bf16x8;
typedef __attribute__((ext_vector_type(8))) ushort u16x8;
typedef __attribute__((ext_vector_type(4))) float  f32x4;

static __device__ __forceinline__ float bf2f(ushort u) {
    union { unsigned int ui; float f; } v; v.ui = ((unsigned int)u) << 16; return v.f;
}
static __device__ __forceinline__ ushort f2bf(float f) {
    union { float f; unsigned int ui; } v; v.f = f;
    unsigned int r = v.ui + 0x7FFFu + ((v.ui >> 16) & 1u);
    return (ushort)(r >> 16);
}

// ---------------- fp32 -> bf16 convert (8 elems/thread) ----------------
__global__ void cvt_kernel(const float* __restrict__ in, ushort* __restrict__ out, long n) {
    long i = ((long)blockIdx.x * blockDim.x + threadIdx.x) * 8;
    if (i >= n) return;
    float4 a = *(const float4*)(in + i);
    float4 b = *(const float4*)(in + i + 4);
    u16x8 v;
    v[0] = f2bf(a.x); v[1] = f2bf(a.y); v[2] = f2bf(a.z); v[3] = f2bf(a.w);
    v[4] = f2bf(b.x); v[5] = f2bf(b.y); v[6] = f2bf(b.z); v[7] = f2bf(b.w);
    *(u16x8*)(out + i) = v;
}

// ---------------- bf16 GEMM: C[M,N] = A[M,K] * B[N,K]^T ----------------
// 128x128 tile, BK=64, 256 threads (4 waves, 2x2), global_load_lds staging.
template<bool F32OUT>
__global__ __launch_bounds__(256) void gemm_bt(const ushort* __restrict__ A,
                                               const ushort* __restrict__ B,
                                               void* __restrict__ C,
                                               int M, int N, int K) {
    __shared__ ushort As[128 * 64];
    __shared__ ushort Bs[128 * 64];
    const int tid  = threadIdx.x;
    const int wave = tid >> 6;
    const int lane = tid & 63;
    const int bm = blockIdx.x, bn = blockIdx.y;
    const int wm = wave >> 1, wn = wave & 1;

    f32x4 acc[4][4];
    #pragma unroll
    for (int i = 0; i < 4; ++i)
        #pragma unroll
        for (int j = 0; j < 4; ++j) { acc[i][j][0]=0.f; acc[i][j][1]=0.f; acc[i][j][2]=0.f; acc[i][j][3]=0.f; }

    const int r_sub  = tid >> 3;          // 0..31 : row within 32-row staging slab
    const int c_el   = (tid & 7) * 8;     // element col offset (8 bf16 = 16B)

    for (int k0 = 0; k0 < K; k0 += 64) {
        #pragma unroll
        for (int it = 0; it < 4; ++it) {
            int row = it * 32 + r_sub;
            const ushort* srcA = A + (size_t)(bm * 128 + row) * K + k0 + c_el;
            const ushort* srcB = B + (size_t)(bn * 128 + row) * K + k0 + c_el;
            __builtin_amdgcn_global_load_lds(
                (const __attribute__((address_space(1))) unsigned int*)srcA,
                (__attribute__((address_space(3))) unsigned int*)((char*)As + it * 4096 + wave * 1024),
                16, 0, 0);
            __builtin_amdgcn_global_load_lds(
                (const __attribute__((address_space(1))) unsigned int*)srcB,
                (__attribute__((address_space(3))) unsigned int*)((char*)Bs + it * 4096 + wave * 1024),
                16, 0, 0);
        }
        __syncthreads();

        const int lr = lane & 15;
        #pragma unroll
        for (int kk = 0; kk < 2; ++kk) {
            const int lk = kk * 32 + (lane >> 4) * 8;
            bf16x8 af[4], bfr[4];
            #pragma unroll
            for (int mi = 0; mi < 4; ++mi)
                af[mi] = *(const bf16x8*)&As[(wm * 64 + mi * 16 + lr) * 64 + lk];
            #pragma unroll
            for (int ni = 0; ni < 4; ++ni)
                bfr[ni] = *(const bf16x8*)&Bs[(wn * 64 + ni * 16 + lr) * 64 + lk];
            #pragma unroll
            for (int mi = 0; mi < 4; ++mi)
                #pragma unroll
                for (int ni = 0; ni < 4; ++ni)
                    acc[mi][ni] = __builtin_amdgcn_mfma_f32_16x16x32_bf16(af[mi], bfr[ni], acc[mi][ni], 0, 0, 0);
        }
        __syncthreads();
    }

    const int lr = lane & 15, lg = lane >> 4;
    #pragma unroll
    for (int mi = 0; mi < 4; ++mi)
        #pragma unroll
        for (int ni = 0; ni < 4; ++ni)
            #pragma unroll
            for (int r = 0; r < 4; ++r) {
                int row = bm * 128 + wm * 64 + mi * 16 + lg * 4 + r;
                int col = bn * 128 + wn * 64 + ni * 16 + lr;
                float v = acc[mi][ni][r];
                if (F32OUT) ((float*)C)[(size_t)row * N + col] = v;
                else        ((ushort*)C)[(size_t)row * N + col] = f2bf(v);
            }
}

// ---------------- RoPE + rearrange into per-head layouts ----------------
__global__ void rope_qk(const ushort* __restrict__ qkv, ushort* __restrict__ Qh, ushort* __restrict__ Kh) {
    const int NQP = BATCH * T_SEQ * HQ * (HD / 2);   // 4,194,304
    int i = blockIdx.x * blockDim.x + threadIdx.x;
    if (i < NQP) {
        int row = i >> 10;
        int idx = i & 1023;
        int h = idx >> 5, j = idx & 31;
        int t = row & (T_SEQ - 1), b = row >> 11;
        const ushort* src = qkv + (size_t)row * NQKV + h * HD + 2 * j;
        unsigned int pin = *(const unsigned int*)src;
        float xr = bf2f((ushort)(pin & 0xFFFF));
        float xi = bf2f((ushort)(pin >> 16));
        float ang = (float)t * exp2f((float)j * -0.4152410118609203f); // 10000^(-j/32)
        float c, s; sincosf(ang, &s, &c);
        float orr = xr * c - xi * s;
        float oi  = xr * s + xi * c;
        unsigned int pout = (unsigned int)f2bf(orr) | ((unsigned int)f2bf(oi) << 16);
        ushort* dst = Qh + ((size_t)((b * HQ + h) * T_SEQ + t)) * HD + 2 * j;
        *(unsigned int*)dst = pout;
    } else {
        int ii = i - NQP;             // K pairs: 1,048,576
        int row = ii >> 8;
        int idx = ii & 255;
        int hk = idx >> 5, j = idx & 31;
        int t = row & (T_SEQ - 1), b = row >> 11;
        const ushort* src = qkv + (size_t)row * NQKV + CDIM + hk * HD + 2 * j;
        unsigned int pin = *(const unsigned int*)src;
        float xr = bf2f((ushort)(pin & 0xFFFF));
        float xi = bf2f((ushort)(pin >> 16));
        float ang = (float)t * exp2f((float)j * -0.4152410118609203f);
        float c, s; sincosf(ang, &s, &c);
        float orr = xr * c - xi * s;
        float oi  = xr * s + xi * c;
        unsigned int pout = (unsigned int)f2bf(orr) | ((unsigned int)f2bf(oi) << 16);
        ushort* dst = Kh + ((size_t)((b * HKV + hk) * T_SEQ + t)) * HD + 2 * j;
        *(unsigned int*)dst = pout;
    }
}

// ---------------- V transpose: qkv V section -> Vt[(b*HKV+hk)*64+d][t] ----------------
__global__ __launch_bounds__(256) void v_transpose(const ushort* __restrict__ qkv, ushort* __restrict__ Vt) {
    __shared__ ushort Vs[64][80];     // pad to 80 elems -> break bank conflicts on transpose read
    int bh = blockIdx.x;              // b*HKV + hk, 0..15
    int tt = blockIdx.y;              // 0..31
    int b = bh >> 3, hk = bh & 7;
    int tid = threadIdx.x;
    #pragma unroll
    for (int c = 0; c < 2; ++c) {
        int rr = tid + c * 256;       // 0..511 -> full 64 rows x 64 cols
        int tl = rr >> 3, d0 = (rr & 7) * 8;
        int row = b * T_SEQ + tt * 64 + tl;
        u16x8 v = *(const u16x8*)(qkv + (size_t)row * NQKV + CDIM + HKV * HD + hk * HD + d0);
        *(u16x8*)&Vs[tl][d0] = v;
    }
    __syncthreads();
    #pragma unroll
    for (int c = 0; c < 2; ++c) {
        int ch = tid + c * 256;
        int d = ch >> 3, t8 = (ch & 7) * 8;
        u16x8 o;
        #pragma unroll
        for (int j = 0; j < 8; ++j) o[j] = Vs[t8 + j][d];
        *(u16x8*)(Vt + ((size_t)(bh * HD + d)) * T_SEQ + tt * 64 + t8) = o;
    }
}

// ---------------- Flash causal GQA attention ----------------
// grid: (16, HQ, B); block p handles q-tiles {p, 31-p} (33 KV tiles each -> balanced).
// 4 waves; wave w owns q rows [qb*64+w*16, +16). LDS tiles XOR-swizzled (T2).
__global__ __launch_bounds__(256) void attn_kernel(const ushort* __restrict__ Qh,
                                                   const ushort* __restrict__ Kh,
                                                   const ushort* __restrict__ Vt,
                                                   ushort* __restrict__ O) {
    __shared__ ushort Ks[64 * 64];
    __shared__ ushort Vs[64 * 64];
    __shared__ ushort Ps[4][16 * 64];
    const int pairi = blockIdx.x, h = blockIdx.y, b = blockIdx.z;
    const int hk = h >> 2;
    const int tid = threadIdx.x, wave = tid >> 6, lane = tid & 63;
    const int lr = lane & 15, lg = lane >> 4;

    const ushort* Kbase = Kh + (size_t)(b * HKV + hk) * T_SEQ * HD;
    const ushort* Vbase = Vt + (size_t)(b * HKV + hk) * HD * T_SEQ;
    const int srow = tid >> 3, scol = (tid & 7) * 8;    // staging: srow 0..31 (+32)
    const int pswz_r = (lr ^ (lr >> 3)) & 7;            // Ps read-row swizzle

    #pragma unroll
    for (int phalf = 0; phalf < 2; ++phalf) {
        const int qb = phalf ? (31 - pairi) : pairi;
        const ushort* Qbase = Qh + ((size_t)((b * HQ + h) * T_SEQ + qb * 64 + wave * 16 + lr)) * HD;
        bf16x8 qf[2];
        qf[0] = *(const bf16x8*)(Qbase + lg * 8);
        qf[1] = *(const bf16x8*)(Qbase + 32 + lg * 8);

        f32x4 oacc[4];
        #pragma unroll
        for (int dt = 0; dt < 4; ++dt) { oacc[dt][0]=0.f; oacc[dt][1]=0.f; oacc[dt][2]=0.f; oacc[dt][3]=0.f; }
        float m_r[4], l_r[4];
        #pragma unroll
        for (int r = 0; r < 4; ++r) { m_r[r] = -INFINITY; l_r[r] = 0.f; }

        const int qrow0 = qb * 64 + wave * 16 + lg * 4;
        const int nkt = qb + 1;

        for (int kt = 0; kt < nkt; ++kt) {
            const int t0 = kt * 64;
            // stage full 64x64 tiles, XOR-swizzled at 16B granularity: blk ^= row&7
            #pragma unroll
            for (int hh = 0; hh < 2; ++hh) {
                int r0 = srow + hh * 32;
                int cb = (((tid & 7) ^ (r0 & 7))) * 8;
                *(u16x8*)&Ks[r0 * 64 + cb] = *(const u16x8*)(Kbase + (size_t)(t0 + r0) * HD + scol);
                *(u16x8*)&Vs[r0 * 64 + cb] = *(const u16x8*)(Vbase + (size_t)r0 * T_SEQ + t0 + scol);
            }
            __syncthreads();

            // S = Q K^T, 4 col-tiles of 16
            f32x4 sacc[4];
            #pragma unroll
            for (int ct = 0; ct < 4; ++ct) { sacc[ct][0]=0.f; sacc[ct][1]=0.f; sacc[ct][2]=0.f; sacc[ct][3]=0.f; }
            __builtin_amdgcn_s_setprio(1);
            #pragma unroll
            for (int kk = 0; kk < 2; ++kk) {
                #pragma unroll
                for (int ct = 0; ct < 4; ++ct) {
                    bf16x8 bfr = *(const bf16x8*)&Ks[(ct * 16 + lr) * 64 + (((kk * 4 + lg) ^ (lr & 7)) * 8)];
                    sacc[ct] = __builtin_amdgcn_mfma_f32_16x16x32_bf16(qf[kk], bfr, sacc[ct], 0, 0, 0);
                }
            }
            __builtin_amdgcn_s_setprio(0);

            // mask + scale
            float sv[4][4];
            #pragma unroll
            for (int ct = 0; ct < 4; ++ct) {
                int colg = t0 + ct * 16 + lr;
                #pragma unroll
                for (int r = 0; r < 4; ++r) {
                    float v = sacc[ct][r] * 0.125f;   // 1/sqrt(64)
                    if (colg > qrow0 + r) v = -INFINITY;
                    sv[ct][r] = v;
                }
            }

            // online softmax per row r (row owned by 16 lanes sharing lg)
            #pragma unroll
            for (int r = 0; r < 4; ++r) {
                float m = sv[0][r];
                m = fmaxf(m, sv[1][r]); m = fmaxf(m, sv[2][r]); m = fmaxf(m, sv[3][r]);
                m = fmaxf(m, __shfl_xor(m, 1));
                m = fmaxf(m, __shfl_xor(m, 2));
                m = fmaxf(m, __shfl_xor(m, 4));
                m = fmaxf(m, __shfl_xor(m, 8));
                float mn = fmaxf(m_r[r], m);
                float alpha = __expf(m_r[r] - mn);
                m_r[r] = mn;
                float lsum = 0.f;
                #pragma unroll
                for (int ct = 0; ct < 4; ++ct) {
                    float p = __expf(sv[ct][r] - mn);
                    sv[ct][r] = p;
                    lsum += p;
                }
                lsum += __shfl_xor(lsum, 1);
                lsum += __shfl_xor(lsum, 2);
                lsum += __shfl_xor(lsum, 4);
                lsum += __shfl_xor(lsum, 8);
                l_r[r] = l_r[r] * alpha + lsum;
                #pragma unroll
                for (int dt = 0; dt < 4; ++dt) oacc[dt][r] *= alpha;
                int prow = lg * 4 + r;
                int psw = (prow ^ (prow >> 3)) & 7;
                #pragma unroll
                for (int ct = 0; ct < 4; ++ct)
                    Ps[wave][prow * 64 + (((ct * 2 + (lr >> 3)) ^ psw) * 8) + (lr & 7)] = f2bf(sv[ct][r]);
            }

            // O += P V
            __builtin_amdgcn_s_setprio(1);
            #pragma unroll
            for (int kk = 0; kk < 2; ++kk) {
                bf16x8 pf = *(const bf16x8*)&Ps[wave][lr * 64 + (((kk * 4 + lg) ^ pswz_r) * 8)];
                #pragma unroll
                for (int dt = 0; dt < 4; ++dt) {
                    bf16x8 vf = *(const bf16x8*)&Vs[(dt * 16 + lr) * 64 + (((kk * 4 + lg) ^ (lr & 7)) * 8)];
                    oacc[dt] = __builtin_amdgcn_mfma_f32_16x16x32_bf16(pf, vf, oacc[dt], 0, 0, 0);
                }
            }
            __builtin_amdgcn_s_setprio(0);
            __syncthreads();
        }

        // normalize + write attOut (bf16, [b*T+t, h*64+d])
        #pragma unroll
        for (int dt = 0; dt < 4; ++dt)
            #pragma unroll
            for (int r = 0; r < 4; ++r) {
                int t = qb * 64 + wave * 16 + lg * 4 + r;
                int d = dt * 16 + lr;
                float v = oacc[dt][r] / l_r[r];
                O[((size_t)(b * T_SEQ + t)) * CDIM + h * HD + d] = f2bf(v);
            }
    }
}

extern "C" void kernel_launch(void* const* d_in, const int* in_sizes, int n_in,
                              void* d_out, int out_size, void* d_ws, size_t ws_size,
                              hipStream_t stream) {
    const float* x  = (const float*)d_in[0];
    const float* Wq = (const float*)d_in[1];
    const float* Wk = (const float*)d_in[2];
    const float* Wv = (const float*)d_in[3];
    const float* Wo = (const float*)d_in[4];
    float* out = (float*)d_out;

    // workspace layout (elements of ushort/bf16)
    ushort* xb    = (ushort*)d_ws;                 //  8,388,608  (x bf16)  [reused as attOut]
    ushort* wqkvb = xb    + 8388608;               //  6,291,456  (Wq|Wk|Wv bf16)
    ushort* wob   = wqkvb + 6291456;               //  4,194,304  (Wo bf16)
    ushort* qkv   = wob   + 4194304;               // 12,582,912  (QKV bf16, ld 3072)
    ushort* Qh    = qkv   + 12582912;              //  8,388,608
    ushort* Kh    = Qh    + 8388608;               //  2,097,152
    ushort* Vt    = Kh    + 2097152;               //  2,097,152
    ushort* attO  = xb;                            // alias: xb dead after QKV GEMM

    // 1) converts
    cvt_kernel<<<4096, 256, 0, stream>>>(x,  xb,    8388608);
    cvt_kernel<<<2048, 256, 0, stream>>>(Wq, wqkvb, 4194304);
    cvt_kernel<<< 512, 256, 0, stream>>>(Wk, wqkvb + 4194304, 1048576);
    cvt_kernel<<< 512, 256, 0, stream>>>(Wv, wqkvb + 5242880, 1048576);
    cvt_kernel<<<2048, 256, 0, stream>>>(Wo, wob,   4194304);

    // 2) fused QKV projection: qkv[4096,3072] = xb[4096,2048] @ wqkvb^T
    gemm_bt<false><<<dim3(32, 24), 256, 0, stream>>>(xb, wqkvb, qkv, 4096, 3072, 2048);

    // 3) RoPE + rearrange
    rope_qk<<<20480, 256, 0, stream>>>(qkv, Qh, Kh);
    v_transpose<<<dim3(16, 32), 256, 0, stream>>>(qkv, Vt);

    // 4) attention (triangle-paired for causal load balance)
    attn_kernel<<<dim3(16, 32, 2), 256, 0, stream>>>(Qh, Kh, Vt, attO);

    // 5) output projection: out[4096,2048] = attO @ wob^T (fp32 out)
    gemm_bt<true><<<dim3(32, 16), 256, 0, stream>>>(attO, wob, out, 4096, 2048, 2048);
}

// Round 5
// 390.109 us; speedup vs baseline: 1.4088x; 1.0510x over previous
//
#include <hip/hip_runtime.h>
#include <hip/hip_bf16.h>
#include <math.h>

#define T_SEQ 2048
#define BATCH 2
#define CDIM  2048
#define HQ    32
#define HKV   8
#define HD    64
#define GRP   4
#define NQKV  3072   // 2048 Q + 512 K + 512 V

typedef __attribute__((ext_vector_type(8))) short  bf16x8;
typedef __attribute__((ext_vector_type(8))) ushort u16x8;
typedef __attribute__((ext_vector_type(4))) float  f32x4;

static __device__ __forceinline__ float bf2f(ushort u) {
    union { unsigned int ui; float f; } v; v.ui = ((unsigned int)u) << 16; return v.f;
}
static __device__ __forceinline__ ushort f2bf(float f) {
    union { float f; unsigned int ui; } v; v.f = f;
    unsigned int r = v.ui + 0x7FFFu + ((v.ui >> 16) & 1u);
    return (ushort)(r >> 16);
}

// ---------------- fp32 -> bf16 convert (8 elems/thread) ----------------
__global__ void cvt_kernel(const float* __restrict__ in, ushort* __restrict__ out, long n) {
    long i = ((long)blockIdx.x * blockDim.x + threadIdx.x) * 8;
    if (i >= n) return;
    float4 a = *(const float4*)(in + i);
    float4 b = *(const float4*)(in + i + 4);
    u16x8 v;
    v[0] = f2bf(a.x); v[1] = f2bf(a.y); v[2] = f2bf(a.z); v[3] = f2bf(a.w);
    v[4] = f2bf(b.x); v[5] = f2bf(b.y); v[6] = f2bf(b.z); v[7] = f2bf(b.w);
    *(u16x8*)(out + i) = v;
}

// ---------------- bf16 GEMM: C[M,N] = A[M,K] * B[N,K]^T ----------------
template<bool F32OUT>
__global__ __launch_bounds__(256) void gemm_bt(const ushort* __restrict__ A,
                                               const ushort* __restrict__ B,
                                               void* __restrict__ C,
                                               int M, int N, int K) {
    __shared__ ushort As[128 * 64];
    __shared__ ushort Bs[128 * 64];
    const int tid  = threadIdx.x;
    const int wave = tid >> 6;
    const int lane = tid & 63;
    const int bm = blockIdx.x, bn = blockIdx.y;
    const int wm = wave >> 1, wn = wave & 1;

    f32x4 acc[4][4];
    #pragma unroll
    for (int i = 0; i < 4; ++i)
        #pragma unroll
        for (int j = 0; j < 4; ++j) { acc[i][j][0]=0.f; acc[i][j][1]=0.f; acc[i][j][2]=0.f; acc[i][j][3]=0.f; }

    const int r_sub  = tid >> 3;
    const int c_el   = (tid & 7) * 8;

    for (int k0 = 0; k0 < K; k0 += 64) {
        #pragma unroll
        for (int it = 0; it < 4; ++it) {
            int row = it * 32 + r_sub;
            const ushort* srcA = A + (size_t)(bm * 128 + row) * K + k0 + c_el;
            const ushort* srcB = B + (size_t)(bn * 128 + row) * K + k0 + c_el;
            __builtin_amdgcn_global_load_lds(
                (const __attribute__((address_space(1))) unsigned int*)srcA,
                (__attribute__((address_space(3))) unsigned int*)((char*)As + it * 4096 + wave * 1024),
                16, 0, 0);
            __builtin_amdgcn_global_load_lds(
                (const __attribute__((address_space(1))) unsigned int*)srcB,
                (__attribute__((address_space(3))) unsigned int*)((char*)Bs + it * 4096 + wave * 1024),
                16, 0, 0);
        }
        __syncthreads();

        const int lr = lane & 15;
        #pragma unroll
        for (int kk = 0; kk < 2; ++kk) {
            const int lk = kk * 32 + (lane >> 4) * 8;
            bf16x8 af[4], bfr[4];
            #pragma unroll
            for (int mi = 0; mi < 4; ++mi)
                af[mi] = *(const bf16x8*)&As[(wm * 64 + mi * 16 + lr) * 64 + lk];
            #pragma unroll
            for (int ni = 0; ni < 4; ++ni)
                bfr[ni] = *(const bf16x8*)&Bs[(wn * 64 + ni * 16 + lr) * 64 + lk];
            #pragma unroll
            for (int mi = 0; mi < 4; ++mi)
                #pragma unroll
                for (int ni = 0; ni < 4; ++ni)
                    acc[mi][ni] = __builtin_amdgcn_mfma_f32_16x16x32_bf16(af[mi], bfr[ni], acc[mi][ni], 0, 0, 0);
        }
        __syncthreads();
    }

    const int lr = lane & 15, lg = lane >> 4;
    #pragma unroll
    for (int mi = 0; mi < 4; ++mi)
        #pragma unroll
        for (int ni = 0; ni < 4; ++ni)
            #pragma unroll
            for (int r = 0; r < 4; ++r) {
                int row = bm * 128 + wm * 64 + mi * 16 + lg * 4 + r;
                int col = bn * 128 + wn * 64 + ni * 16 + lr;
                float v = acc[mi][ni][r];
                if (F32OUT) ((float*)C)[(size_t)row * N + col] = v;
                else        ((ushort*)C)[(size_t)row * N + col] = f2bf(v);
            }
}

// ---------------- RoPE + rearrange into per-head layouts ----------------
__global__ void rope_qk(const ushort* __restrict__ qkv, ushort* __restrict__ Qh, ushort* __restrict__ Kh) {
    const int NQP = BATCH * T_SEQ * HQ * (HD / 2);   // 4,194,304
    int i = blockIdx.x * blockDim.x + threadIdx.x;
    if (i < NQP) {
        int row = i >> 10;
        int idx = i & 1023;
        int h = idx >> 5, j = idx & 31;
        int t = row & (T_SEQ - 1), b = row >> 11;
        const ushort* src = qkv + (size_t)row * NQKV + h * HD + 2 * j;
        unsigned int pin = *(const unsigned int*)src;
        float xr = bf2f((ushort)(pin & 0xFFFF));
        float xi = bf2f((ushort)(pin >> 16));
        float ang = (float)t * exp2f((float)j * -0.4152410118609203f); // 10000^(-j/32)
        float c, s; sincosf(ang, &s, &c);
        float orr = xr * c - xi * s;
        float oi  = xr * s + xi * c;
        unsigned int pout = (unsigned int)f2bf(orr) | ((unsigned int)f2bf(oi) << 16);
        ushort* dst = Qh + ((size_t)((b * HQ + h) * T_SEQ + t)) * HD + 2 * j;
        *(unsigned int*)dst = pout;
    } else {
        int ii = i - NQP;             // K pairs: 1,048,576
        int row = ii >> 8;
        int idx = ii & 255;
        int hk = idx >> 5, j = idx & 31;
        int t = row & (T_SEQ - 1), b = row >> 11;
        const ushort* src = qkv + (size_t)row * NQKV + CDIM + hk * HD + 2 * j;
        unsigned int pin = *(const unsigned int*)src;
        float xr = bf2f((ushort)(pin & 0xFFFF));
        float xi = bf2f((ushort)(pin >> 16));
        float ang = (float)t * exp2f((float)j * -0.4152410118609203f);
        float c, s; sincosf(ang, &s, &c);
        float orr = xr * c - xi * s;
        float oi  = xr * s + xi * c;
        unsigned int pout = (unsigned int)f2bf(orr) | ((unsigned int)f2bf(oi) << 16);
        ushort* dst = Kh + ((size_t)((b * HKV + hk) * T_SEQ + t)) * HD + 2 * j;
        *(unsigned int*)dst = pout;
    }
}

// ---------------- V transpose: qkv V section -> Vt[(b*HKV+hk)*64+d][t] ----------------
__global__ __launch_bounds__(256) void v_transpose(const ushort* __restrict__ qkv, ushort* __restrict__ Vt) {
    __shared__ ushort Vs[64][80];
    int bh = blockIdx.x;
    int tt = blockIdx.y;
    int b = bh >> 3, hk = bh & 7;
    int tid = threadIdx.x;
    #pragma unroll
    for (int c = 0; c < 2; ++c) {
        int rr = tid + c * 256;
        int tl = rr >> 3, d0 = (rr & 7) * 8;
        int row = b * T_SEQ + tt * 64 + tl;
        u16x8 v = *(const u16x8*)(qkv + (size_t)row * NQKV + CDIM + HKV * HD + hk * HD + d0);
        *(u16x8*)&Vs[tl][d0] = v;
    }
    __syncthreads();
    #pragma unroll
    for (int c = 0; c < 2; ++c) {
        int ch = tid + c * 256;
        int d = ch >> 3, t8 = (ch & 7) * 8;
        u16x8 o;
        #pragma unroll
        for (int j = 0; j < 8; ++j) o[j] = Vs[t8 + j][d];
        *(u16x8*)(Vt + ((size_t)(bh * HD + d)) * T_SEQ + tt * 64 + t8) = o;
    }
}

// ---------------- Flash causal GQA attention ----------------
// grid: (16, HQ, B); block p handles q-tiles {p, 31-p} (33 KV tiles -> balanced).
// LDS double-buffered K/V (reg-staged prefetch), XOR-swizzled (T2).
// Softmax: raw-score max, scale folded into exp2, defer-max rescale (T13),
// row sums via ones-MFMA (no shfl sum), mask only on diagonal tile.
__global__ __launch_bounds__(256) void attn_kernel(const ushort* __restrict__ Qh,
                                                   const ushort* __restrict__ Kh,
                                                   const ushort* __restrict__ Vt,
                                                   ushort* __restrict__ O) {
    __shared__ ushort Ks[2][64 * 64];
    __shared__ ushort Vs[2][64 * 64];
    __shared__ ushort Ps[4][16 * 64];
    const int pairi = blockIdx.x, h = blockIdx.y, b = blockIdx.z;
    const int hk = h >> 2;
    const int tid = threadIdx.x, wave = tid >> 6, lane = tid & 63;
    const int lr = lane & 15, lg = lane >> 4;
    const float CEXP = 0.1803368801111204f;   // (1/sqrt(64)) * log2(e)

    const ushort* Kbase = Kh + (size_t)(b * HKV + hk) * T_SEQ * HD;
    const ushort* Vbase = Vt + (size_t)(b * HKV + hk) * HD * T_SEQ;
    const int srow = tid >> 3, scol = (tid & 7) * 8;
    const int pswz_r = (lr ^ (lr >> 3)) & 7;

    bf16x8 onesf;
    #pragma unroll
    for (int j = 0; j < 8; ++j) onesf[j] = (short)0x3F80;   // bf16 1.0

    #pragma unroll
    for (int phalf = 0; phalf < 2; ++phalf) {
        const int qb = phalf ? (31 - pairi) : pairi;
        const ushort* Qbase = Qh + ((size_t)((b * HQ + h) * T_SEQ + qb * 64 + wave * 16 + lr)) * HD;
        bf16x8 qf[2];
        qf[0] = *(const bf16x8*)(Qbase + lg * 8);
        qf[1] = *(const bf16x8*)(Qbase + 32 + lg * 8);

        f32x4 oacc[4];
        #pragma unroll
        for (int dt = 0; dt < 4; ++dt) { oacc[dt][0]=0.f; oacc[dt][1]=0.f; oacc[dt][2]=0.f; oacc[dt][3]=0.f; }
        float m_r[4], l_r[4];
        #pragma unroll
        for (int r = 0; r < 4; ++r) { m_r[r] = -INFINITY; l_r[r] = 0.f; }

        const int qrow0 = qb * 64 + wave * 16 + lg * 4;
        const int nkt = qb + 1;

        // prologue: stage tile 0 into regs
        u16x8 rK[2], rV[2];
        #pragma unroll
        for (int hh = 0; hh < 2; ++hh) {
            int r0 = srow + hh * 32;
            rK[hh] = *(const u16x8*)(Kbase + (size_t)r0 * HD + scol);
            rV[hh] = *(const u16x8*)(Vbase + (size_t)r0 * T_SEQ + scol);
        }
        __syncthreads();   // protect LDS reuse across phalf passes

        for (int kt = 0; kt < nkt; ++kt) {
            const int t0 = kt * 64;
            const int buf = kt & 1;
            // write staged regs -> LDS (XOR swizzle at 16B granularity)
            #pragma unroll
            for (int hh = 0; hh < 2; ++hh) {
                int r0 = srow + hh * 32;
                int cb = (((tid & 7) ^ (r0 & 7))) * 8;
                *(u16x8*)&Ks[buf][r0 * 64 + cb] = rK[hh];
                *(u16x8*)&Vs[buf][r0 * 64 + cb] = rV[hh];
            }
            // issue prefetch for next tile (overlaps barrier + compute)
            if (kt + 1 < nkt) {
                const int t1 = t0 + 64;
                #pragma unroll
                for (int hh = 0; hh < 2; ++hh) {
                    int r0 = srow + hh * 32;
                    rK[hh] = *(const u16x8*)(Kbase + (size_t)(t1 + r0) * HD + scol);
                    rV[hh] = *(const u16x8*)(Vbase + (size_t)r0 * T_SEQ + t1 + scol);
                }
            }
            __syncthreads();

            // S = Q K^T (raw, unscaled), 4 col-tiles of 16
            f32x4 sacc[4];
            #pragma unroll
            for (int ct = 0; ct < 4; ++ct) { sacc[ct][0]=0.f; sacc[ct][1]=0.f; sacc[ct][2]=0.f; sacc[ct][3]=0.f; }
            __builtin_amdgcn_s_setprio(1);
            #pragma unroll
            for (int kk = 0; kk < 2; ++kk) {
                #pragma unroll
                for (int ct = 0; ct < 4; ++ct) {
                    bf16x8 bfr = *(const bf16x8*)&Ks[buf][(ct * 16 + lr) * 64 + (((kk * 4 + lg) ^ (lr & 7)) * 8)];
                    sacc[ct] = __builtin_amdgcn_mfma_f32_16x16x32_bf16(qf[kk], bfr, sacc[ct], 0, 0, 0);
                }
            }
            __builtin_amdgcn_s_setprio(0);

            float sv[4][4];
            #pragma unroll
            for (int ct = 0; ct < 4; ++ct)
                #pragma unroll
                for (int r = 0; r < 4; ++r) sv[ct][r] = sacc[ct][r];

            // causal mask: only the diagonal tile needs it
            if (kt == qb) {
                #pragma unroll
                for (int ct = 0; ct < 4; ++ct) {
                    int colg = t0 + ct * 16 + lr;
                    #pragma unroll
                    for (int r = 0; r < 4; ++r)
                        if (colg > qrow0 + r) sv[ct][r] = -INFINITY;
                }
            }

            // per-row tile max (raw units)
            float pm[4];
            #pragma unroll
            for (int r = 0; r < 4; ++r) {
                float m = fmaxf(fmaxf(sv[0][r], sv[1][r]), fmaxf(sv[2][r], sv[3][r]));
                m = fmaxf(m, __shfl_xor(m, 1));
                m = fmaxf(m, __shfl_xor(m, 2));
                m = fmaxf(m, __shfl_xor(m, 4));
                m = fmaxf(m, __shfl_xor(m, 8));
                pm[r] = m;
            }

            // defer-max: skip rescale when growth <= 8 nats (=64 raw) for ALL rows
            bool cskip = (pm[0] <= m_r[0] + 64.f) && (pm[1] <= m_r[1] + 64.f) &&
                         (pm[2] <= m_r[2] + 64.f) && (pm[3] <= m_r[3] + 64.f);
            if (!__all(cskip)) {
                #pragma unroll
                for (int r = 0; r < 4; ++r) {
                    float mn = fmaxf(m_r[r], pm[r]);
                    float al = exp2f(CEXP * (m_r[r] - mn));
                    m_r[r] = mn;
                    l_r[r] *= al;
                    #pragma unroll
                    for (int dt = 0; dt < 4; ++dt) oacc[dt][r] *= al;
                }
            }

            // P = exp2(C*(s-m)) -> Ps (bf16, swizzled)
            #pragma unroll
            for (int r = 0; r < 4; ++r) {
                int prow = lg * 4 + r;
                int psw = (prow ^ (prow >> 3)) & 7;
                #pragma unroll
                for (int ct = 0; ct < 4; ++ct) {
                    float p = exp2f(CEXP * (sv[ct][r] - m_r[r]));
                    Ps[wave][prow * 64 + (((ct * 2 + (lr >> 3)) ^ psw) * 8) + (lr & 7)] = f2bf(p);
                }
            }

            // O += P V ; row sums via ones-MFMA (reuses pf fragments)
            f32x4 lacc;
            lacc[0]=0.f; lacc[1]=0.f; lacc[2]=0.f; lacc[3]=0.f;
            __builtin_amdgcn_s_setprio(1);
            #pragma unroll
            for (int kk = 0; kk < 2; ++kk) {
                bf16x8 pf = *(const bf16x8*)&Ps[wave][lr * 64 + (((kk * 4 + lg) ^ pswz_r) * 8)];
                lacc = __builtin_amdgcn_mfma_f32_16x16x32_bf16(pf, onesf, lacc, 0, 0, 0);
                #pragma unroll
                for (int dt = 0; dt < 4; ++dt) {
                    bf16x8 vf = *(const bf16x8*)&Vs[buf][(dt * 16 + lr) * 64 + (((kk * 4 + lg) ^ (lr & 7)) * 8)];
                    oacc[dt] = __builtin_amdgcn_mfma_f32_16x16x32_bf16(pf, vf, oacc[dt], 0, 0, 0);
                }
            }
            __builtin_amdgcn_s_setprio(0);
            #pragma unroll
            for (int r = 0; r < 4; ++r) l_r[r] += lacc[r];
        }

        // normalize + write attOut (bf16, [b*T+t, h*64+d])
        #pragma unroll
        for (int dt = 0; dt < 4; ++dt)
            #pragma unroll
            for (int r = 0; r < 4; ++r) {
                int t = qb * 64 + wave * 16 + lg * 4 + r;
                int d = dt * 16 + lr;
                float v = oacc[dt][r] / l_r[r];
                O[((size_t)(b * T_SEQ + t)) * CDIM + h * HD + d] = f2bf(v);
            }
    }
}

extern "C" void kernel_launch(void* const* d_in, const int* in_sizes, int n_in,
                              void* d_out, int out_size, void* d_ws, size_t ws_size,
                              hipStream_t stream) {
    const float* x  = (const float*)d_in[0];
    const float* Wq = (const float*)d_in[1];
    const float* Wk = (const float*)d_in[2];
    const float* Wv = (const float*)d_in[3];
    const float* Wo = (const float*)d_in[4];
    float* out = (float*)d_out;

    ushort* xb    = (ushort*)d_ws;                 //  8,388,608  (x bf16)  [reused as attOut]
    ushort* wqkvb = xb    + 8388608;               //  6,291,456
    ushort* wob   = wqkvb + 6291456;               //  4,194,304
    ushort* qkv   = wob   + 4194304;               // 12,582,912
    ushort* Qh    = qkv   + 12582912;              //  8,388,608
    ushort* Kh    = Qh    + 8388608;               //  2,097,152
    ushort* Vt    = Kh    + 2097152;               //  2,097,152
    ushort* attO  = xb;

    cvt_kernel<<<4096, 256, 0, stream>>>(x,  xb,    8388608);
    cvt_kernel<<<2048, 256, 0, stream>>>(Wq, wqkvb, 4194304);
    cvt_kernel<<< 512, 256, 0, stream>>>(Wk, wqkvb + 4194304, 1048576);
    cvt_kernel<<< 512, 256, 0, stream>>>(Wv, wqkvb + 5242880, 1048576);
    cvt_kernel<<<2048, 256, 0, stream>>>(Wo, wob,   4194304);

    gemm_bt<false><<<dim3(32, 24), 256, 0, stream>>>(xb, wqkvb, qkv, 4096, 3072, 2048);

    rope_qk<<<20480, 256, 0, stream>>>(qkv, Qh, Kh);
    v_transpose<<<dim3(16, 32), 256, 0, stream>>>(qkv, Vt);

    attn_kernel<<<dim3(16, 32, 2), 256, 0, stream>>>(Qh, Kh, Vt, attO);

    gemm_bt<true><<<dim3(32, 16), 256, 0, stream>>>(attO, wob, out, 4096, 2048, 2048);
}

// Round 6
// 364.782 us; speedup vs baseline: 1.5066x; 1.0694x over previous
//
#include <hip/hip_runtime.h>
#include <hip/hip_bf16.h>
#include <math.h>

#define T_SEQ 2048
#define BATCH 2
#define CDIM  2048
#define HQ    32
#define HKV   8
#define HD    64
#define GRP   4
#define NQKV  3072   // 2048 Q + 512 K + 512 V

typedef __attribute__((ext_vector_type(8))) short  bf16x8;
typedef __attribute__((ext_vector_type(8))) ushort u16x8;
typedef __attribute__((ext_vector_type(4))) float  f32x4;

static __device__ __forceinline__ float bf2f(ushort u) {
    union { unsigned int ui; float f; } v; v.ui = ((unsigned int)u) << 16; return v.f;
}
static __device__ __forceinline__ ushort f2bf(float f) {
    union { float f; unsigned int ui; } v; v.f = f;
    unsigned int r = v.ui + 0x7FFFu + ((v.ui >> 16) & 1u);
    return (ushort)(r >> 16);
}
// packed 2x f32 -> bf16x2 (emits v_cvt_pk_bf16_f32)
static __device__ __forceinline__ unsigned int pack2bf(float a, float b) {
    __hip_bfloat162 h = __float22bfloat162_rn(float2{a, b});
    union { __hip_bfloat162 h; unsigned int u; } v; v.h = h; return v.u;
}

// ---------------- fp32 -> bf16 convert (8 elems/thread) ----------------
__global__ void cvt_kernel(const float* __restrict__ in, ushort* __restrict__ out, long n) {
    long i = ((long)blockIdx.x * blockDim.x + threadIdx.x) * 8;
    if (i >= n) return;
    float4 a = *(const float4*)(in + i);
    float4 b = *(const float4*)(in + i + 4);
    u16x8 v;
    v[0] = f2bf(a.x); v[1] = f2bf(a.y); v[2] = f2bf(a.z); v[3] = f2bf(a.w);
    v[4] = f2bf(b.x); v[5] = f2bf(b.y); v[6] = f2bf(b.z); v[7] = f2bf(b.w);
    *(u16x8*)(out + i) = v;
}

// ---------------- bf16 GEMM: C[M,N] = A[M,K] * B[N,K]^T ----------------
template<bool F32OUT>
__global__ __launch_bounds__(256) void gemm_bt(const ushort* __restrict__ A,
                                               const ushort* __restrict__ B,
                                               void* __restrict__ C,
                                               int M, int N, int K) {
    __shared__ ushort As[128 * 64];
    __shared__ ushort Bs[128 * 64];
    const int tid  = threadIdx.x;
    const int wave = tid >> 6;
    const int lane = tid & 63;
    const int bm = blockIdx.x, bn = blockIdx.y;
    const int wm = wave >> 1, wn = wave & 1;

    f32x4 acc[4][4];
    #pragma unroll
    for (int i = 0; i < 4; ++i)
        #pragma unroll
        for (int j = 0; j < 4; ++j) { acc[i][j][0]=0.f; acc[i][j][1]=0.f; acc[i][j][2]=0.f; acc[i][j][3]=0.f; }

    const int r_sub  = tid >> 3;
    const int c_el   = (tid & 7) * 8;

    for (int k0 = 0; k0 < K; k0 += 64) {
        #pragma unroll
        for (int it = 0; it < 4; ++it) {
            int row = it * 32 + r_sub;
            const ushort* srcA = A + (size_t)(bm * 128 + row) * K + k0 + c_el;
            const ushort* srcB = B + (size_t)(bn * 128 + row) * K + k0 + c_el;
            __builtin_amdgcn_global_load_lds(
                (const __attribute__((address_space(1))) unsigned int*)srcA,
                (__attribute__((address_space(3))) unsigned int*)((char*)As + it * 4096 + wave * 1024),
                16, 0, 0);
            __builtin_amdgcn_global_load_lds(
                (const __attribute__((address_space(1))) unsigned int*)srcB,
                (__attribute__((address_space(3))) unsigned int*)((char*)Bs + it * 4096 + wave * 1024),
                16, 0, 0);
        }
        __syncthreads();

        const int lr = lane & 15;
        #pragma unroll
        for (int kk = 0; kk < 2; ++kk) {
            const int lk = kk * 32 + (lane >> 4) * 8;
            bf16x8 af[4], bfr[4];
            #pragma unroll
            for (int mi = 0; mi < 4; ++mi)
                af[mi] = *(const bf16x8*)&As[(wm * 64 + mi * 16 + lr) * 64 + lk];
            #pragma unroll
            for (int ni = 0; ni < 4; ++ni)
                bfr[ni] = *(const bf16x8*)&Bs[(wn * 64 + ni * 16 + lr) * 64 + lk];
            #pragma unroll
            for (int mi = 0; mi < 4; ++mi)
                #pragma unroll
                for (int ni = 0; ni < 4; ++ni)
                    acc[mi][ni] = __builtin_amdgcn_mfma_f32_16x16x32_bf16(af[mi], bfr[ni], acc[mi][ni], 0, 0, 0);
        }
        __syncthreads();
    }

    const int lr = lane & 15, lg = lane >> 4;
    #pragma unroll
    for (int mi = 0; mi < 4; ++mi)
        #pragma unroll
        for (int ni = 0; ni < 4; ++ni)
            #pragma unroll
            for (int r = 0; r < 4; ++r) {
                int row = bm * 128 + wm * 64 + mi * 16 + lg * 4 + r;
                int col = bn * 128 + wn * 64 + ni * 16 + lr;
                float v = acc[mi][ni][r];
                if (F32OUT) ((float*)C)[(size_t)row * N + col] = v;
                else        ((ushort*)C)[(size_t)row * N + col] = f2bf(v);
            }
}

// ---------------- RoPE + rearrange into per-head layouts ----------------
__global__ void rope_qk(const ushort* __restrict__ qkv, ushort* __restrict__ Qh, ushort* __restrict__ Kh) {
    const int NQP = BATCH * T_SEQ * HQ * (HD / 2);   // 4,194,304
    int i = blockIdx.x * blockDim.x + threadIdx.x;
    if (i < NQP) {
        int row = i >> 10;
        int idx = i & 1023;
        int h = idx >> 5, j = idx & 31;
        int t = row & (T_SEQ - 1), b = row >> 11;
        const ushort* src = qkv + (size_t)row * NQKV + h * HD + 2 * j;
        unsigned int pin = *(const unsigned int*)src;
        float xr = bf2f((ushort)(pin & 0xFFFF));
        float xi = bf2f((ushort)(pin >> 16));
        float ang = (float)t * exp2f((float)j * -0.4152410118609203f); // 10000^(-j/32)
        float c, s; sincosf(ang, &s, &c);
        float orr = xr * c - xi * s;
        float oi  = xr * s + xi * c;
        unsigned int pout = (unsigned int)f2bf(orr) | ((unsigned int)f2bf(oi) << 16);
        ushort* dst = Qh + ((size_t)((b * HQ + h) * T_SEQ + t)) * HD + 2 * j;
        *(unsigned int*)dst = pout;
    } else {
        int ii = i - NQP;             // K pairs: 1,048,576
        int row = ii >> 8;
        int idx = ii & 255;
        int hk = idx >> 5, j = idx & 31;
        int t = row & (T_SEQ - 1), b = row >> 11;
        const ushort* src = qkv + (size_t)row * NQKV + CDIM + hk * HD + 2 * j;
        unsigned int pin = *(const unsigned int*)src;
        float xr = bf2f((ushort)(pin & 0xFFFF));
        float xi = bf2f((ushort)(pin >> 16));
        float ang = (float)t * exp2f((float)j * -0.4152410118609203f);
        float c, s; sincosf(ang, &s, &c);
        float orr = xr * c - xi * s;
        float oi  = xr * s + xi * c;
        unsigned int pout = (unsigned int)f2bf(orr) | ((unsigned int)f2bf(oi) << 16);
        ushort* dst = Kh + ((size_t)((b * HKV + hk) * T_SEQ + t)) * HD + 2 * j;
        *(unsigned int*)dst = pout;
    }
}

// ---------------- V transpose: qkv V section -> Vt[(b*HKV+hk)*64+d][t] ----------------
__global__ __launch_bounds__(256) void v_transpose(const ushort* __restrict__ qkv, ushort* __restrict__ Vt) {
    __shared__ ushort Vs[64][80];
    int bh = blockIdx.x;
    int tt = blockIdx.y;
    int b = bh >> 3, hk = bh & 7;
    int tid = threadIdx.x;
    #pragma unroll
    for (int c = 0; c < 2; ++c) {
        int rr = tid + c * 256;
        int tl = rr >> 3, d0 = (rr & 7) * 8;
        int row = b * T_SEQ + tt * 64 + tl;
        u16x8 v = *(const u16x8*)(qkv + (size_t)row * NQKV + CDIM + HKV * HD + hk * HD + d0);
        *(u16x8*)&Vs[tl][d0] = v;
    }
    __syncthreads();
    #pragma unroll
    for (int c = 0; c < 2; ++c) {
        int ch = tid + c * 256;
        int d = ch >> 3, t8 = (ch & 7) * 8;
        u16x8 o;
        #pragma unroll
        for (int j = 0; j < 8; ++j) o[j] = Vs[t8 + j][d];
        *(u16x8*)(Vt + ((size_t)(bh * HD + d)) * T_SEQ + tt * 64 + t8) = o;
    }
}

// ---------------- Flash causal GQA attention ----------------
// grid: (16, HQ, B); block p handles q-tiles {p, 31-p} (33 KV tiles -> balanced).
// SWAPPED QK^T: sacc = mfma(K, Q) -> lane holds S[k=ct*16+lg*4+r][q=lr].
// Row-softmax is per-lane + 2 shfls; P packed via cvt_pk, 4x ds_write_b64.
__global__ __launch_bounds__(256) void attn_kernel(const ushort* __restrict__ Qh,
                                                   const ushort* __restrict__ Kh,
                                                   const ushort* __restrict__ Vt,
                                                   ushort* __restrict__ O) {
    __shared__ ushort Ks[2][64 * 64];
    __shared__ ushort Vs[2][64 * 64];
    __shared__ ushort Ps[4][16 * 64];
    const int pairi = blockIdx.x, h = blockIdx.y, b = blockIdx.z;
    const int hk = h >> 2;
    const int tid = threadIdx.x, wave = tid >> 6, lane = tid & 63;
    const int lr = lane & 15, lg = lane >> 4;
    const float CEXP = 0.1803368801111204f;   // (1/sqrt(64)) * log2(e)

    const ushort* Kbase = Kh + (size_t)(b * HKV + hk) * T_SEQ * HD;
    const ushort* Vbase = Vt + (size_t)(b * HKV + hk) * HD * T_SEQ;
    const int srow = tid >> 3, scol = (tid & 7) * 8;
    const int psw = (lr ^ (lr >> 3)) & 7;     // Ps swizzle for q-row lr (write AND read)

    bf16x8 onesf;
    #pragma unroll
    for (int j = 0; j < 8; ++j) onesf[j] = (short)0x3F80;   // bf16 1.0

    #pragma unroll
    for (int phalf = 0; phalf < 2; ++phalf) {
        const int qb = phalf ? (31 - pairi) : pairi;
        const ushort* Qbase = Qh + ((size_t)((b * HQ + h) * T_SEQ + qb * 64 + wave * 16 + lr)) * HD;
        bf16x8 qf[2];
        qf[0] = *(const bf16x8*)(Qbase + lg * 8);
        qf[1] = *(const bf16x8*)(Qbase + 32 + lg * 8);

        f32x4 oacc[4];
        #pragma unroll
        for (int dt = 0; dt < 4; ++dt) { oacc[dt][0]=0.f; oacc[dt][1]=0.f; oacc[dt][2]=0.f; oacc[dt][3]=0.f; }
        float l_r[4];
        #pragma unroll
        for (int r = 0; r < 4; ++r) l_r[r] = 0.f;
        float m_run = -INFINITY;              // running max for q-row lr (raw units)

        const int q_glob = qb * 64 + wave * 16 + lr;
        const int nkt = qb + 1;

        // prologue: stage tile 0 into regs
        u16x8 rK[2], rV[2];
        #pragma unroll
        for (int hh = 0; hh < 2; ++hh) {
            int r0 = srow + hh * 32;
            rK[hh] = *(const u16x8*)(Kbase + (size_t)r0 * HD + scol);
            rV[hh] = *(const u16x8*)(Vbase + (size_t)r0 * T_SEQ + scol);
        }
        __syncthreads();   // protect LDS reuse across phalf passes

        for (int kt = 0; kt < nkt; ++kt) {
            const int t0 = kt * 64;
            const int buf = kt & 1;
            // write staged regs -> LDS (XOR swizzle at 16B granularity)
            #pragma unroll
            for (int hh = 0; hh < 2; ++hh) {
                int r0 = srow + hh * 32;
                int cb = (((tid & 7) ^ (r0 & 7))) * 8;
                *(u16x8*)&Ks[buf][r0 * 64 + cb] = rK[hh];
                *(u16x8*)&Vs[buf][r0 * 64 + cb] = rV[hh];
            }
            // issue prefetch for next tile (overlaps barrier + compute)
            if (kt + 1 < nkt) {
                const int t1 = t0 + 64;
                #pragma unroll
                for (int hh = 0; hh < 2; ++hh) {
                    int r0 = srow + hh * 32;
                    rK[hh] = *(const u16x8*)(Kbase + (size_t)(t1 + r0) * HD + scol);
                    rV[hh] = *(const u16x8*)(Vbase + (size_t)r0 * T_SEQ + t1 + scol);
                }
            }
            __syncthreads();

            // S^T = K Q^T : sacc[ct][r] = S[k=t0+ct*16+lg*4+r][q=lr]
            f32x4 sacc[4];
            #pragma unroll
            for (int ct = 0; ct < 4; ++ct) { sacc[ct][0]=0.f; sacc[ct][1]=0.f; sacc[ct][2]=0.f; sacc[ct][3]=0.f; }
            __builtin_amdgcn_s_setprio(1);
            #pragma unroll
            for (int kk = 0; kk < 2; ++kk) {
                #pragma unroll
                for (int ct = 0; ct < 4; ++ct) {
                    bf16x8 kf = *(const bf16x8*)&Ks[buf][(ct * 16 + lr) * 64 + (((kk * 4 + lg) ^ (lr & 7)) * 8)];
                    sacc[ct] = __builtin_amdgcn_mfma_f32_16x16x32_bf16(kf, qf[kk], sacc[ct], 0, 0, 0);
                }
            }
            __builtin_amdgcn_s_setprio(0);

            // causal mask: only the diagonal tile needs it
            if (kt == qb) {
                #pragma unroll
                for (int ct = 0; ct < 4; ++ct) {
                    #pragma unroll
                    for (int r = 0; r < 4; ++r) {
                        int k_glob = t0 + ct * 16 + lg * 4 + r;
                        if (k_glob > q_glob) sacc[ct][r] = -INFINITY;
                    }
                }
            }

            // per-q-row tile max: 15 local fmax + 2 shfls (over lg)
            float pm = sacc[0][0];
            #pragma unroll
            for (int ct = 0; ct < 4; ++ct)
                #pragma unroll
                for (int r = 0; r < 4; ++r) pm = fmaxf(pm, sacc[ct][r]);
            pm = fmaxf(pm, __shfl_xor(pm, 16));
            pm = fmaxf(pm, __shfl_xor(pm, 32));

            // defer-max: skip rescale when growth <= 64 raw (~8 nats) for all rows
            bool cskip = (pm <= m_run + 64.f);
            if (!__all(cskip)) {
                float mn = fmaxf(m_run, pm);
                float al = exp2f(CEXP * (m_run - mn));
                m_run = mn;
                #pragma unroll
                for (int r = 0; r < 4; ++r) {
                    float alq = __shfl(al, lg * 4 + r);   // alpha for q-row lg*4+r
                    l_r[r] *= alq;
                    #pragma unroll
                    for (int dt = 0; dt < 4; ++dt) oacc[dt][r] *= alq;
                }
            }

            // P = exp2(C*(s-m)); pack 4 k-values per ct -> one ds_write_b64
            const float cm = CEXP * m_run;
            #pragma unroll
            for (int ct = 0; ct < 4; ++ct) {
                float p0 = exp2f(fmaf(CEXP, sacc[ct][0], -cm));
                float p1 = exp2f(fmaf(CEXP, sacc[ct][1], -cm));
                float p2 = exp2f(fmaf(CEXP, sacc[ct][2], -cm));
                float p3 = exp2f(fmaf(CEXP, sacc[ct][3], -cm));
                uint2 w; w.x = pack2bf(p0, p1); w.y = pack2bf(p2, p3);
                // element addr: q*64 + ((ct*2+(lg>>1)) ^ psw)*8 + (lg&1)*4
                *(uint2*)&Ps[wave][lr * 64 + (((ct * 2 + (lg >> 1)) ^ psw) * 8) + (lg & 1) * 4] = w;
            }

            // O += P V ; row sums via ones-MFMA (reuses pf fragments)
            f32x4 lacc;
            lacc[0]=0.f; lacc[1]=0.f; lacc[2]=0.f; lacc[3]=0.f;
            __builtin_amdgcn_s_setprio(1);
            #pragma unroll
            for (int kk = 0; kk < 2; ++kk) {
                bf16x8 pf = *(const bf16x8*)&Ps[wave][lr * 64 + (((kk * 4 + lg) ^ psw) * 8)];
                lacc = __builtin_amdgcn_mfma_f32_16x16x32_bf16(pf, onesf, lacc, 0, 0, 0);
                #pragma unroll
                for (int dt = 0; dt < 4; ++dt) {
                    bf16x8 vf = *(const bf16x8*)&Vs[buf][(dt * 16 + lr) * 64 + (((kk * 4 + lg) ^ (lr & 7)) * 8)];
                    oacc[dt] = __builtin_amdgcn_mfma_f32_16x16x32_bf16(pf, vf, oacc[dt], 0, 0, 0);
                }
            }
            __builtin_amdgcn_s_setprio(0);
            #pragma unroll
            for (int r = 0; r < 4; ++r) l_r[r] += lacc[r];
        }

        // normalize + write attOut (bf16, [b*T+t, h*64+d])
        #pragma unroll
        for (int dt = 0; dt < 4; ++dt)
            #pragma unroll
            for (int r = 0; r < 4; ++r) {
                int t = qb * 64 + wave * 16 + lg * 4 + r;
                int d = dt * 16 + lr;
                float v = oacc[dt][r] / l_r[r];
                O[((size_t)(b * T_SEQ + t)) * CDIM + h * HD + d] = f2bf(v);
            }
    }
}

extern "C" void kernel_launch(void* const* d_in, const int* in_sizes, int n_in,
                              void* d_out, int out_size, void* d_ws, size_t ws_size,
                              hipStream_t stream) {
    const float* x  = (const float*)d_in[0];
    const float* Wq = (const float*)d_in[1];
    const float* Wk = (const float*)d_in[2];
    const float* Wv = (const float*)d_in[3];
    const float* Wo = (const float*)d_in[4];
    float* out = (float*)d_out;

    ushort* xb    = (ushort*)d_ws;                 //  8,388,608  (x bf16)  [reused as attOut]
    ushort* wqkvb = xb    + 8388608;               //  6,291,456
    ushort* wob   = wqkvb + 6291456;               //  4,194,304
    ushort* qkv   = wob   + 4194304;               // 12,582,912
    ushort* Qh    = qkv   + 12582912;              //  8,388,608
    ushort* Kh    = Qh    + 8388608;               //  2,097,152
    ushort* Vt    = Kh    + 2097152;               //  2,097,152
    ushort* attO  = xb;

    cvt_kernel<<<4096, 256, 0, stream>>>(x,  xb,    8388608);
    cvt_kernel<<<2048, 256, 0, stream>>>(Wq, wqkvb, 4194304);
    cvt_kernel<<< 512, 256, 0, stream>>>(Wk, wqkvb + 4194304, 1048576);
    cvt_kernel<<< 512, 256, 0, stream>>>(Wv, wqkvb + 5242880, 1048576);
    cvt_kernel<<<2048, 256, 0, stream>>>(Wo, wob,   4194304);

    gemm_bt<false><<<dim3(32, 24), 256, 0, stream>>>(xb, wqkvb, qkv, 4096, 3072, 2048);

    rope_qk<<<20480, 256, 0, stream>>>(qkv, Qh, Kh);
    v_transpose<<<dim3(16, 32), 256, 0, stream>>>(qkv, Vt);

    attn_kernel<<<dim3(16, 32, 2), 256, 0, stream>>>(Qh, Kh, Vt, attO);

    gemm_bt<true><<<dim3(32, 16), 256, 0, stream>>>(attO, wob, out, 4096, 2048, 2048);
}

// Round 8
// 323.096 us; speedup vs baseline: 1.7010x; 1.1290x over previous
//
#include <hip/hip_runtime.h>
#include <hip/hip_bf16.h>
#include <math.h>

#define T_SEQ 2048
#define BATCH 2
#define CDIM  2048
#define HQ    32
#define HKV   8
#define HD    64
#define GRP   4
#define NQKV  3072   // 2048 Q + 512 K + 512 V

typedef __attribute__((ext_vector_type(8))) short  bf16x8;
typedef __attribute__((ext_vector_type(8))) ushort u16x8;
typedef __attribute__((ext_vector_type(4))) float  f32x4;

static __device__ __forceinline__ float bf2f(ushort u) {
    union { unsigned int ui; float f; } v; v.ui = ((unsigned int)u) << 16; return v.f;
}
static __device__ __forceinline__ ushort f2bf(float f) {
    union { float f; unsigned int ui; } v; v.f = f;
    unsigned int r = v.ui + 0x7FFFu + ((v.ui >> 16) & 1u);
    return (ushort)(r >> 16);
}
// packed 2x f32 -> bf16x2 (emits v_cvt_pk_bf16_f32)
static __device__ __forceinline__ unsigned int pack2bf(float a, float b) {
    __hip_bfloat162 h = __float22bfloat162_rn(float2{a, b});
    union { __hip_bfloat162 h; unsigned int u; } v; v.h = h; return v.u;
}

// ---------------- fused fp32 -> bf16 convert of all 5 inputs ----------------
// chunk = 8 elems. Segments (chunks): x 1048576 | Wq 524288 | Wk 131072 | Wv 131072 | Wo 524288
__global__ void cvt5_kernel(const float* __restrict__ x,  const float* __restrict__ wq,
                            const float* __restrict__ wk, const float* __restrict__ wv,
                            const float* __restrict__ wo,
                            ushort* __restrict__ xb, ushort* __restrict__ wqkvb,
                            ushort* __restrict__ wob) {
    long c = (long)blockIdx.x * blockDim.x + threadIdx.x;
    const float* src; ushort* dst; long off;
    if (c < 1048576L)      { src = x;  dst = xb;              off = c; }
    else if (c < 1572864L) { src = wq; dst = wqkvb;           off = c - 1048576L; }
    else if (c < 1703936L) { src = wk; dst = wqkvb + 4194304; off = c - 1572864L; }
    else if (c < 1835008L) { src = wv; dst = wqkvb + 5242880; off = c - 1703936L; }
    else                   { src = wo; dst = wob;             off = c - 1835008L; }
    long i = off * 8;
    float4 a = *(const float4*)(src + i);
    float4 b = *(const float4*)(src + i + 4);
    u16x8 v;
    v[0] = f2bf(a.x); v[1] = f2bf(a.y); v[2] = f2bf(a.z); v[3] = f2bf(a.w);
    v[4] = f2bf(b.x); v[5] = f2bf(b.y); v[6] = f2bf(b.z); v[7] = f2bf(b.w);
    *(u16x8*)(dst + i) = v;
}

// ---------------- bf16 GEMM: C[M,N] = A[M,K] * B[N,K]^T ----------------
// 128x128 tile, BK=64, 4 waves. Stage-ahead double-buffered global_load_lds
// (T3-min), XOR-swizzled LDS via pre-swizzled global source (T2, rule #21),
// XCD-aware bijective block swizzle (T1; grids here are multiples of 8).
template<bool F32OUT>
__global__ __launch_bounds__(256) void gemm_bt(const ushort* __restrict__ A,
                                               const ushort* __restrict__ B,
                                               void* __restrict__ C,
                                               int M, int N, int K) {
    __shared__ ushort As[2][128 * 64];
    __shared__ ushort Bs[2][128 * 64];
    const int tid  = threadIdx.x;
    const int wave = tid >> 6;
    const int lane = tid & 63;

    const int nbx = gridDim.x;
    int wg = blockIdx.y * nbx + blockIdx.x;
    const int nwg = nbx * gridDim.y;
    const int cpx = nwg >> 3;                  // nwg % 8 == 0 for all our grids
    wg = (wg & 7) * cpx + (wg >> 3);           // bijective XCD swizzle
    const int bm = wg % nbx, bn = wg / nbx;
    const int wm = wave >> 1, wn = wave & 1;

    f32x4 acc[4][4];
    #pragma unroll
    for (int i = 0; i < 4; ++i)
        #pragma unroll
        for (int j = 0; j < 4; ++j) { acc[i][j][0]=0.f; acc[i][j][1]=0.f; acc[i][j][2]=0.f; acc[i][j][3]=0.f; }

    const int r_sub = tid >> 3;                          // 0..31
    const int c_src = (((tid & 7) ^ (r_sub & 7))) * 8;   // pre-swizzled source col (16B blk)
    const int lr = lane & 15, lg = lane >> 4;

    const int nkt = K >> 6;

    auto STAGE = [&](int k0, int db) {
        #pragma unroll
        for (int it = 0; it < 4; ++it) {
            int row = it * 32 + r_sub;
            const ushort* srcA = A + (size_t)(bm * 128 + row) * K + k0 + c_src;
            const ushort* srcB = B + (size_t)(bn * 128 + row) * K + k0 + c_src;
            __builtin_amdgcn_global_load_lds(
                (const __attribute__((address_space(1))) unsigned int*)srcA,
                (__attribute__((address_space(3))) unsigned int*)((char*)&As[db][0] + it * 4096 + wave * 1024),
                16, 0, 0);
            __builtin_amdgcn_global_load_lds(
                (const __attribute__((address_space(1))) unsigned int*)srcB,
                (__attribute__((address_space(3))) unsigned int*)((char*)&Bs[db][0] + it * 4096 + wave * 1024),
                16, 0, 0);
        }
    };

    STAGE(0, 0);
    __syncthreads();   // drains vmcnt -> buf0 ready

    for (int t = 0; t < nkt; ++t) {
        const int db = t & 1;
        if (t + 1 < nkt) STAGE((t + 1) << 6, db ^ 1);   // prefetch next tile, other buffer

        #pragma unroll
        for (int kk = 0; kk < 2; ++kk) {
            bf16x8 af[4], bfr[4];
            #pragma unroll
            for (int mi = 0; mi < 4; ++mi)
                af[mi] = *(const bf16x8*)&As[db][(wm * 64 + mi * 16 + lr) * 64 + (((kk * 4 + lg) ^ (lr & 7)) * 8)];
            #pragma unroll
            for (int ni = 0; ni < 4; ++ni)
                bfr[ni] = *(const bf16x8*)&Bs[db][(wn * 64 + ni * 16 + lr) * 64 + (((kk * 4 + lg) ^ (lr & 7)) * 8)];
            __builtin_amdgcn_s_setprio(1);
            #pragma unroll
            for (int mi = 0; mi < 4; ++mi)
                #pragma unroll
                for (int ni = 0; ni < 4; ++ni)
                    acc[mi][ni] = __builtin_amdgcn_mfma_f32_16x16x32_bf16(af[mi], bfr[ni], acc[mi][ni], 0, 0, 0);
            __builtin_amdgcn_s_setprio(0);
        }
        __syncthreads();   // waits prefetch (vmcnt0) + all waves done reading buf db
    }

    #pragma unroll
    for (int mi = 0; mi < 4; ++mi)
        #pragma unroll
        for (int ni = 0; ni < 4; ++ni)
            #pragma unroll
            for (int r = 0; r < 4; ++r) {
                int row = bm * 128 + wm * 64 + mi * 16 + lg * 4 + r;
                int col = bn * 128 + wn * 64 + ni * 16 + lr;
                float v = acc[mi][ni][r];
                if (F32OUT) ((float*)C)[(size_t)row * N + col] = v;
                else        ((ushort*)C)[(size_t)row * N + col] = f2bf(v);
            }
}

// ---------------- RoPE + rearrange into per-head layouts ----------------
__global__ void rope_qk(const ushort* __restrict__ qkv, ushort* __restrict__ Qh, ushort* __restrict__ Kh) {
    const int NQP = BATCH * T_SEQ * HQ * (HD / 2);   // 4,194,304
    int i = blockIdx.x * blockDim.x + threadIdx.x;
    if (i < NQP) {
        int row = i >> 10;
        int idx = i & 1023;
        int h = idx >> 5, j = idx & 31;
        int t = row & (T_SEQ - 1), b = row >> 11;
        const ushort* src = qkv + (size_t)row * NQKV + h * HD + 2 * j;
        unsigned int pin = *(const unsigned int*)src;
        float xr = bf2f((ushort)(pin & 0xFFFF));
        float xi = bf2f((ushort)(pin >> 16));
        float ang = (float)t * exp2f((float)j * -0.4152410118609203f); // 10000^(-j/32)
        float c, s; sincosf(ang, &s, &c);
        float orr = xr * c - xi * s;
        float oi  = xr * s + xi * c;
        unsigned int pout = (unsigned int)f2bf(orr) | ((unsigned int)f2bf(oi) << 16);
        ushort* dst = Qh + ((size_t)((b * HQ + h) * T_SEQ + t)) * HD + 2 * j;
        *(unsigned int*)dst = pout;
    } else {
        int ii = i - NQP;             // K pairs: 1,048,576
        int row = ii >> 8;
        int idx = ii & 255;
        int hk = idx >> 5, j = idx & 31;
        int t = row & (T_SEQ - 1), b = row >> 11;
        const ushort* src = qkv + (size_t)row * NQKV + CDIM + hk * HD + 2 * j;
        unsigned int pin = *(const unsigned int*)src;
        float xr = bf2f((ushort)(pin & 0xFFFF));
        float xi = bf2f((ushort)(pin >> 16));
        float ang = (float)t * exp2f((float)j * -0.4152410118609203f);
        float c, s; sincosf(ang, &s, &c);
        float orr = xr * c - xi * s;
        float oi  = xr * s + xi * c;
        unsigned int pout = (unsigned int)f2bf(orr) | ((unsigned int)f2bf(oi) << 16);
        ushort* dst = Kh + ((size_t)((b * HKV + hk) * T_SEQ + t)) * HD + 2 * j;
        *(unsigned int*)dst = pout;
    }
}

// ---------------- V transpose: qkv V section -> Vt[(b*HKV+hk)*64+d][t] ----------------
__global__ __launch_bounds__(256) void v_transpose(const ushort* __restrict__ qkv, ushort* __restrict__ Vt) {
    __shared__ ushort Vs[64][80];
    int bh = blockIdx.x;
    int tt = blockIdx.y;
    int b = bh >> 3, hk = bh & 7;
    int tid = threadIdx.x;
    #pragma unroll
    for (int c = 0; c < 2; ++c) {
        int rr = tid + c * 256;
        int tl = rr >> 3, d0 = (rr & 7) * 8;
        int row = b * T_SEQ + tt * 64 + tl;
        u16x8 v = *(const u16x8*)(qkv + (size_t)row * NQKV + CDIM + HKV * HD + hk * HD + d0);
        *(u16x8*)&Vs[tl][d0] = v;
    }
    __syncthreads();
    #pragma unroll
    for (int c = 0; c < 2; ++c) {
        int ch = tid + c * 256;
        int d = ch >> 3, t8 = (ch & 7) * 8;
        u16x8 o;
        #pragma unroll
        for (int j = 0; j < 8; ++j) o[j] = Vs[t8 + j][d];
        *(u16x8*)(Vt + ((size_t)(bh * HD + d)) * T_SEQ + tt * 64 + t8) = o;
    }
}

// ---------------- Flash causal GQA attention ----------------
// grid: (16, HQ, B); block p handles q-tiles {p, 31-p} (33 KV tiles -> balanced).
// SWAPPED QK^T: sacc = mfma(K, Q) -> lane holds S[k=ct*16+lg*4+r][q=lr].
// Row-softmax is per-lane + 2 shfls; P packed via cvt_pk, 4x ds_write_b64.
__global__ __launch_bounds__(256) void attn_kernel(const ushort* __restrict__ Qh,
                                                   const ushort* __restrict__ Kh,
                                                   const ushort* __restrict__ Vt,
                                                   ushort* __restrict__ O) {
    __shared__ ushort Ks[2][64 * 64];
    __shared__ ushort Vs[2][64 * 64];
    __shared__ ushort Ps[4][16 * 64];
    const int pairi = blockIdx.x, h = blockIdx.y, b = blockIdx.z;
    const int hk = h >> 2;
    const int tid = threadIdx.x, wave = tid >> 6, lane = tid & 63;
    const int lr = lane & 15, lg = lane >> 4;
    const float CEXP = 0.1803368801111204f;   // (1/sqrt(64)) * log2(e)

    const ushort* Kbase = Kh + (size_t)(b * HKV + hk) * T_SEQ * HD;
    const ushort* Vbase = Vt + (size_t)(b * HKV + hk) * HD * T_SEQ;
    const int srow = tid >> 3, scol = (tid & 7) * 8;
    const int psw = (lr ^ (lr >> 3)) & 7;     // Ps swizzle for q-row lr (write AND read)

    bf16x8 onesf;
    #pragma unroll
    for (int j = 0; j < 8; ++j) onesf[j] = (short)0x3F80;   // bf16 1.0

    #pragma unroll
    for (int phalf = 0; phalf < 2; ++phalf) {
        const int qb = phalf ? (31 - pairi) : pairi;
        const ushort* Qbase = Qh + ((size_t)((b * HQ + h) * T_SEQ + qb * 64 + wave * 16 + lr)) * HD;
        bf16x8 qf[2];
        qf[0] = *(const bf16x8*)(Qbase + lg * 8);
        qf[1] = *(const bf16x8*)(Qbase + 32 + lg * 8);

        f32x4 oacc[4];
        #pragma unroll
        for (int dt = 0; dt < 4; ++dt) { oacc[dt][0]=0.f; oacc[dt][1]=0.f; oacc[dt][2]=0.f; oacc[dt][3]=0.f; }
        float l_r[4];
        #pragma unroll
        for (int r = 0; r < 4; ++r) l_r[r] = 0.f;
        float m_run = -INFINITY;              // running max for q-row lr (raw units)

        const int q_glob = qb * 64 + wave * 16 + lr;
        const int nkt = qb + 1;

        // prologue: stage tile 0 into regs
        u16x8 rK[2], rV[2];
        #pragma unroll
        for (int hh = 0; hh < 2; ++hh) {
            int r0 = srow + hh * 32;
            rK[hh] = *(const u16x8*)(Kbase + (size_t)r0 * HD + scol);
            rV[hh] = *(const u16x8*)(Vbase + (size_t)r0 * T_SEQ + scol);
        }
        __syncthreads();   // protect LDS reuse across phalf passes

        for (int kt = 0; kt < nkt; ++kt) {
            const int t0 = kt * 64;
            const int buf = kt & 1;
            // write staged regs -> LDS (XOR swizzle at 16B granularity)
            #pragma unroll
            for (int hh = 0; hh < 2; ++hh) {
                int r0 = srow + hh * 32;
                int cb = (((tid & 7) ^ (r0 & 7))) * 8;
                *(u16x8*)&Ks[buf][r0 * 64 + cb] = rK[hh];
                *(u16x8*)&Vs[buf][r0 * 64 + cb] = rV[hh];
            }
            // issue prefetch for next tile (overlaps barrier + compute)
            if (kt + 1 < nkt) {
                const int t1 = t0 + 64;
                #pragma unroll
                for (int hh = 0; hh < 2; ++hh) {
                    int r0 = srow + hh * 32;
                    rK[hh] = *(const u16x8*)(Kbase + (size_t)(t1 + r0) * HD + scol);
                    rV[hh] = *(const u16x8*)(Vbase + (size_t)r0 * T_SEQ + t1 + scol);
                }
            }
            __syncthreads();

            // S^T = K Q^T : sacc[ct][r] = S[k=t0+ct*16+lg*4+r][q=lr]
            f32x4 sacc[4];
            #pragma unroll
            for (int ct = 0; ct < 4; ++ct) { sacc[ct][0]=0.f; sacc[ct][1]=0.f; sacc[ct][2]=0.f; sacc[ct][3]=0.f; }
            __builtin_amdgcn_s_setprio(1);
            #pragma unroll
            for (int kk = 0; kk < 2; ++kk) {
                #pragma unroll
                for (int ct = 0; ct < 4; ++ct) {
                    bf16x8 kf = *(const bf16x8*)&Ks[buf][(ct * 16 + lr) * 64 + (((kk * 4 + lg) ^ (lr & 7)) * 8)];
                    sacc[ct] = __builtin_amdgcn_mfma_f32_16x16x32_bf16(kf, qf[kk], sacc[ct], 0, 0, 0);
                }
            }
            __builtin_amdgcn_s_setprio(0);

            // causal mask: only the diagonal tile needs it
            if (kt == qb) {
                #pragma unroll
                for (int ct = 0; ct < 4; ++ct) {
                    #pragma unroll
                    for (int r = 0; r < 4; ++r) {
                        int k_glob = t0 + ct * 16 + lg * 4 + r;
                        if (k_glob > q_glob) sacc[ct][r] = -INFINITY;
                    }
                }
            }

            // per-q-row tile max: 15 local fmax + 2 shfls (over lg)
            float pm = sacc[0][0];
            #pragma unroll
            for (int ct = 0; ct < 4; ++ct)
                #pragma unroll
                for (int r = 0; r < 4; ++r) pm = fmaxf(pm, sacc[ct][r]);
            pm = fmaxf(pm, __shfl_xor(pm, 16));
            pm = fmaxf(pm, __shfl_xor(pm, 32));

            // defer-max: skip rescale when growth <= 64 raw (~8 nats) for all rows
            bool cskip = (pm <= m_run + 64.f);
            if (!__all(cskip)) {
                float mn = fmaxf(m_run, pm);
                float al = exp2f(CEXP * (m_run - mn));
                m_run = mn;
                #pragma unroll
                for (int r = 0; r < 4; ++r) {
                    float alq = __shfl(al, lg * 4 + r);   // alpha for q-row lg*4+r
                    l_r[r] *= alq;
                    #pragma unroll
                    for (int dt = 0; dt < 4; ++dt) oacc[dt][r] *= alq;
                }
            }

            // P = exp2(C*(s-m)); pack 4 k-values per ct -> one ds_write_b64
            const float cm = CEXP * m_run;
            #pragma unroll
            for (int ct = 0; ct < 4; ++ct) {
                float p0 = exp2f(fmaf(CEXP, sacc[ct][0], -cm));
                float p1 = exp2f(fmaf(CEXP, sacc[ct][1], -cm));
                float p2 = exp2f(fmaf(CEXP, sacc[ct][2], -cm));
                float p3 = exp2f(fmaf(CEXP, sacc[ct][3], -cm));
                uint2 w; w.x = pack2bf(p0, p1); w.y = pack2bf(p2, p3);
                // element addr: q*64 + ((ct*2+(lg>>1)) ^ psw)*8 + (lg&1)*4
                *(uint2*)&Ps[wave][lr * 64 + (((ct * 2 + (lg >> 1)) ^ psw) * 8) + (lg & 1) * 4] = w;
            }

            // O += P V ; row sums via ones-MFMA (reuses pf fragments)
            f32x4 lacc;
            lacc[0]=0.f; lacc[1]=0.f; lacc[2]=0.f; lacc[3]=0.f;
            __builtin_amdgcn_s_setprio(1);
            #pragma unroll
            for (int kk = 0; kk < 2; ++kk) {
                bf16x8 pf = *(const bf16x8*)&Ps[wave][lr * 64 + (((kk * 4 + lg) ^ psw) * 8)];
                lacc = __builtin_amdgcn_mfma_f32_16x16x32_bf16(pf, onesf, lacc, 0, 0, 0);
                #pragma unroll
                for (int dt = 0; dt < 4; ++dt) {
                    bf16x8 vf = *(const bf16x8*)&Vs[buf][(dt * 16 + lr) * 64 + (((kk * 4 + lg) ^ (lr & 7)) * 8)];
                    oacc[dt] = __builtin_amdgcn_mfma_f32_16x16x32_bf16(pf, vf, oacc[dt], 0, 0, 0);
                }
            }
            __builtin_amdgcn_s_setprio(0);
            #pragma unroll
            for (int r = 0; r < 4; ++r) l_r[r] += lacc[r];
        }

        // normalize + write attOut (bf16, [b*T+t, h*64+d])
        #pragma unroll
        for (int dt = 0; dt < 4; ++dt)
            #pragma unroll
            for (int r = 0; r < 4; ++r) {
                int t = qb * 64 + wave * 16 + lg * 4 + r;
                int d = dt * 16 + lr;
                float v = oacc[dt][r] / l_r[r];
                O[((size_t)(b * T_SEQ + t)) * CDIM + h * HD + d] = f2bf(v);
            }
    }
}

extern "C" void kernel_launch(void* const* d_in, const int* in_sizes, int n_in,
                              void* d_out, int out_size, void* d_ws, size_t ws_size,
                              hipStream_t stream) {
    const float* x  = (const float*)d_in[0];
    const float* Wq = (const float*)d_in[1];
    const float* Wk = (const float*)d_in[2];
    const float* Wv = (const float*)d_in[3];
    const float* Wo = (const float*)d_in[4];
    float* out = (float*)d_out;

    ushort* xb    = (ushort*)d_ws;                 //  8,388,608  (x bf16)  [reused as attOut]
    ushort* wqkvb = xb    + 8388608;               //  6,291,456
    ushort* wob   = wqkvb + 6291456;               //  4,194,304
    ushort* qkv   = wob   + 4194304;               // 12,582,912
    ushort* Qh    = qkv   + 12582912;              //  8,388,608
    ushort* Kh    = Qh    + 8388608;               //  2,097,152
    ushort* Vt    = Kh    + 2097152;               //  2,097,152
    ushort* attO  = xb;

    // 1) fused converts (one launch): 2,359,296 chunks / 256
    cvt5_kernel<<<9216, 256, 0, stream>>>(x, Wq, Wk, Wv, Wo, xb, wqkvb, wob);

    // 2) fused QKV projection: qkv[4096,3072] = xb[4096,2048] @ wqkvb^T
    gemm_bt<false><<<dim3(32, 24), 256, 0, stream>>>(xb, wqkvb, qkv, 4096, 3072, 2048);

    // 3) RoPE + rearrange
    rope_qk<<<20480, 256, 0, stream>>>(qkv, Qh, Kh);
    v_transpose<<<dim3(16, 32), 256, 0, stream>>>(qkv, Vt);

    // 4) attention (triangle-paired for causal load balance)
    attn_kernel<<<dim3(16, 32, 2), 256, 0, stream>>>(Qh, Kh, Vt, attO);

    // 5) output projection: out[4096,2048] = attO @ wob^T (fp32 out)
    gemm_bt<true><<<dim3(32, 16), 256, 0, stream>>>(attO, wob, out, 4096, 2048, 2048);
}

// Round 10
// 306.052 us; speedup vs baseline: 1.7957x; 1.0557x over previous
//
#include <hip/hip_runtime.h>
#include <hip/hip_bf16.h>
#include <math.h>

#define T_SEQ 2048
#define BATCH 2
#define CDIM  2048
#define HQ    32
#define HKV   8
#define HD    64
#define GRP   4
#define NQKV  3072   // 2048 Q + 512 K + 512 V

typedef __attribute__((ext_vector_type(8))) short  bf16x8;
typedef __attribute__((ext_vector_type(8))) ushort u16x8;
typedef __attribute__((ext_vector_type(4))) float  f32x4;

static __device__ __forceinline__ float bf2f(ushort u) {
    union { unsigned int ui; float f; } v; v.ui = ((unsigned int)u) << 16; return v.f;
}
static __device__ __forceinline__ ushort f2bf(float f) {
    union { float f; unsigned int ui; } v; v.f = f;
    unsigned int r = v.ui + 0x7FFFu + ((v.ui >> 16) & 1u);
    return (ushort)(r >> 16);
}
// packed 2x f32 -> bf16x2 (emits v_cvt_pk_bf16_f32)
static __device__ __forceinline__ unsigned int pack2bf(float a, float b) {
    __hip_bfloat162 h = __float22bfloat162_rn(float2{a, b});
    union { __hip_bfloat162 h; unsigned int u; } v; v.h = h; return v.u;
}

// ---------------- fused fp32 -> bf16 convert of all 5 inputs ----------------
__global__ void cvt5_kernel(const float* __restrict__ x,  const float* __restrict__ wq,
                            const float* __restrict__ wk, const float* __restrict__ wv,
                            const float* __restrict__ wo,
                            ushort* __restrict__ xb, ushort* __restrict__ wqkvb,
                            ushort* __restrict__ wob) {
    long c = (long)blockIdx.x * blockDim.x + threadIdx.x;
    const float* src; ushort* dst; long off;
    if (c < 1048576L)      { src = x;  dst = xb;              off = c; }
    else if (c < 1572864L) { src = wq; dst = wqkvb;           off = c - 1048576L; }
    else if (c < 1703936L) { src = wk; dst = wqkvb + 4194304; off = c - 1572864L; }
    else if (c < 1835008L) { src = wv; dst = wqkvb + 5242880; off = c - 1703936L; }
    else                   { src = wo; dst = wob;             off = c - 1835008L; }
    long i = off * 8;
    float4 a = *(const float4*)(src + i);
    float4 b = *(const float4*)(src + i + 4);
    u16x8 v;
    v[0] = f2bf(a.x); v[1] = f2bf(a.y); v[2] = f2bf(a.z); v[3] = f2bf(a.w);
    v[4] = f2bf(b.x); v[5] = f2bf(b.y); v[6] = f2bf(b.z); v[7] = f2bf(b.w);
    *(u16x8*)(dst + i) = v;
}

// ---------------- bf16 GEMM: C[M,N] = A[M,K] * B[N,K]^T ----------------
// 128x128 tile, BK=64, double-buffered gload_lds, T2 swizzle, T1 XCD swizzle.
template<bool F32OUT>
__global__ __launch_bounds__(256) void gemm_bt(const ushort* __restrict__ A,
                                               const ushort* __restrict__ B,
                                               void* __restrict__ C,
                                               int M, int N, int K) {
    __shared__ ushort As[2][128 * 64];
    __shared__ ushort Bs[2][128 * 64];
    const int tid  = threadIdx.x;
    const int wave = tid >> 6;
    const int lane = tid & 63;

    const int nbx = gridDim.x;
    int wg = blockIdx.y * nbx + blockIdx.x;
    const int nwg = nbx * gridDim.y;
    const int cpx = nwg >> 3;
    wg = (wg & 7) * cpx + (wg >> 3);           // bijective XCD swizzle
    const int bm = wg % nbx, bn = wg / nbx;
    const int wm = wave >> 1, wn = wave & 1;

    f32x4 acc[4][4];
    #pragma unroll
    for (int i = 0; i < 4; ++i)
        #pragma unroll
        for (int j = 0; j < 4; ++j) { acc[i][j][0]=0.f; acc[i][j][1]=0.f; acc[i][j][2]=0.f; acc[i][j][3]=0.f; }

    const int r_sub = tid >> 3;
    const int c_src = (((tid & 7) ^ (r_sub & 7))) * 8;
    const int lr = lane & 15, lg = lane >> 4;

    const int nkt = K >> 6;

    auto STAGE = [&](int k0, int db) {
        #pragma unroll
        for (int it = 0; it < 4; ++it) {
            int row = it * 32 + r_sub;
            const ushort* srcA = A + (size_t)(bm * 128 + row) * K + k0 + c_src;
            const ushort* srcB = B + (size_t)(bn * 128 + row) * K + k0 + c_src;
            __builtin_amdgcn_global_load_lds(
                (const __attribute__((address_space(1))) unsigned int*)srcA,
                (__attribute__((address_space(3))) unsigned int*)((char*)&As[db][0] + it * 4096 + wave * 1024),
                16, 0, 0);
            __builtin_amdgcn_global_load_lds(
                (const __attribute__((address_space(1))) unsigned int*)srcB,
                (__attribute__((address_space(3))) unsigned int*)((char*)&Bs[db][0] + it * 4096 + wave * 1024),
                16, 0, 0);
        }
    };

    STAGE(0, 0);
    __syncthreads();

    for (int t = 0; t < nkt; ++t) {
        const int db = t & 1;
        if (t + 1 < nkt) STAGE((t + 1) << 6, db ^ 1);

        #pragma unroll
        for (int kk = 0; kk < 2; ++kk) {
            bf16x8 af[4], bfr[4];
            #pragma unroll
            for (int mi = 0; mi < 4; ++mi)
                af[mi] = *(const bf16x8*)&As[db][(wm * 64 + mi * 16 + lr) * 64 + (((kk * 4 + lg) ^ (lr & 7)) * 8)];
            #pragma unroll
            for (int ni = 0; ni < 4; ++ni)
                bfr[ni] = *(const bf16x8*)&Bs[db][(wn * 64 + ni * 16 + lr) * 64 + (((kk * 4 + lg) ^ (lr & 7)) * 8)];
            __builtin_amdgcn_s_setprio(1);
            #pragma unroll
            for (int mi = 0; mi < 4; ++mi)
                #pragma unroll
                for (int ni = 0; ni < 4; ++ni)
                    acc[mi][ni] = __builtin_amdgcn_mfma_f32_16x16x32_bf16(af[mi], bfr[ni], acc[mi][ni], 0, 0, 0);
            __builtin_amdgcn_s_setprio(0);
        }
        __syncthreads();
    }

    #pragma unroll
    for (int mi = 0; mi < 4; ++mi)
        #pragma unroll
        for (int ni = 0; ni < 4; ++ni)
            #pragma unroll
            for (int r = 0; r < 4; ++r) {
                int row = bm * 128 + wm * 64 + mi * 16 + lg * 4 + r;
                int col = bn * 128 + wn * 64 + ni * 16 + lr;
                float v = acc[mi][ni][r];
                if (F32OUT) ((float*)C)[(size_t)row * N + col] = v;
                else        ((ushort*)C)[(size_t)row * N + col] = f2bf(v);
            }
}

// ---------------- RoPE + rearrange into per-head layouts ----------------
__global__ void rope_qk(const ushort* __restrict__ qkv, ushort* __restrict__ Qh, ushort* __restrict__ Kh) {
    const int NQP = BATCH * T_SEQ * HQ * (HD / 2);   // 4,194,304
    int i = blockIdx.x * blockDim.x + threadIdx.x;
    if (i < NQP) {
        int row = i >> 10;
        int idx = i & 1023;
        int h = idx >> 5, j = idx & 31;
        int t = row & (T_SEQ - 1), b = row >> 11;
        const ushort* src = qkv + (size_t)row * NQKV + h * HD + 2 * j;
        unsigned int pin = *(const unsigned int*)src;
        float xr = bf2f((ushort)(pin & 0xFFFF));
        float xi = bf2f((ushort)(pin >> 16));
        float ang = (float)t * exp2f((float)j * -0.4152410118609203f); // 10000^(-j/32)
        float c, s; sincosf(ang, &s, &c);
        float orr = xr * c - xi * s;
        float oi  = xr * s + xi * c;
        unsigned int pout = (unsigned int)f2bf(orr) | ((unsigned int)f2bf(oi) << 16);
        ushort* dst = Qh + ((size_t)((b * HQ + h) * T_SEQ + t)) * HD + 2 * j;
        *(unsigned int*)dst = pout;
    } else {
        int ii = i - NQP;             // K pairs: 1,048,576
        int row = ii >> 8;
        int idx = ii & 255;
        int hk = idx >> 5, j = idx & 31;
        int t = row & (T_SEQ - 1), b = row >> 11;
        const ushort* src = qkv + (size_t)row * NQKV + CDIM + hk * HD + 2 * j;
        unsigned int pin = *(const unsigned int*)src;
        float xr = bf2f((ushort)(pin & 0xFFFF));
        float xi = bf2f((ushort)(pin >> 16));
        float ang = (float)t * exp2f((float)j * -0.4152410118609203f);
        float c, s; sincosf(ang, &s, &c);
        float orr = xr * c - xi * s;
        float oi  = xr * s + xi * c;
        unsigned int pout = (unsigned int)f2bf(orr) | ((unsigned int)f2bf(oi) << 16);
        ushort* dst = Kh + ((size_t)((b * HKV + hk) * T_SEQ + t)) * HD + 2 * j;
        *(unsigned int*)dst = pout;
    }
}

// ---------------- V transpose: qkv V section -> Vt[(b*HKV+hk)*64+d][t] ----------------
__global__ __launch_bounds__(256) void v_transpose(const ushort* __restrict__ qkv, ushort* __restrict__ Vt) {
    __shared__ ushort Vs[64][80];
    int bh = blockIdx.x;
    int tt = blockIdx.y;
    int b = bh >> 3, hk = bh & 7;
    int tid = threadIdx.x;
    #pragma unroll
    for (int c = 0; c < 2; ++c) {
        int rr = tid + c * 256;
        int tl = rr >> 3, d0 = (rr & 7) * 8;
        int row = b * T_SEQ + tt * 64 + tl;
        u16x8 v = *(const u16x8*)(qkv + (size_t)row * NQKV + CDIM + HKV * HD + hk * HD + d0);
        *(u16x8*)&Vs[tl][d0] = v;
    }
    __syncthreads();
    #pragma unroll
    for (int c = 0; c < 2; ++c) {
        int ch = tid + c * 256;
        int d = ch >> 3, t8 = (ch & 7) * 8;
        u16x8 o;
        #pragma unroll
        for (int j = 0; j < 8; ++j) o[j] = Vs[t8 + j][d];
        *(u16x8*)(Vt + ((size_t)(bh * HD + d)) * T_SEQ + tt * 64 + t8) = o;
    }
}

// ---------------- Flash causal GQA attention (8-wave, QBLK=128) ----------------
// grid: (8, HQ, B), 512 threads. Block p handles q-tiles {p, 15-p} of 128 rows
// (34 KV tiles each -> balanced). Wave w owns q rows [qb*128+w*16, +16).
// Staging: each thread stages ONE 16B K chunk + ONE 16B V chunk per tile
// (halved vs 4-wave). Pointers strength-reduced; fully-future tiles skipped.
__global__ __launch_bounds__(512) void attn_kernel(const ushort* __restrict__ Qh,
                                                   const ushort* __restrict__ Kh,
                                                   const ushort* __restrict__ Vt,
                                                   ushort* __restrict__ O) {
    __shared__ ushort Ks[2][64 * 64];
    __shared__ ushort Vs[2][64 * 64];
    __shared__ ushort Ps[8][16 * 64];
    const int pairi = blockIdx.x, h = blockIdx.y, b = blockIdx.z;
    const int hk = h >> 2;
    const int tid = threadIdx.x, wave = tid >> 6, lane = tid & 63;
    const int lr = lane & 15, lg = lane >> 4;
    const float CEXP = 0.1803368801111204f;   // (1/sqrt(64)) * log2(e)

    const ushort* Kbase = Kh + (size_t)(b * HKV + hk) * T_SEQ * HD;
    const ushort* Vbase = Vt + (size_t)(b * HKV + hk) * HD * T_SEQ;
    const int srow = tid >> 3, scol = (tid & 7) * 8;       // srow 0..63
    const int psw = (lr ^ (lr >> 3)) & 7;

    // hoisted LDS addresses (both double-buffer variants)
    const int swofs = srow * 64 + (((tid & 7) ^ (srow & 7)) * 8);
    ushort* const kw0 = &Ks[0][swofs]; ushort* const kw1 = &Ks[1][swofs];
    ushort* const vw0 = &Vs[0][swofs]; ushort* const vw1 = &Vs[1][swofs];
    int rdk[2];                                            // fragment k-offsets
    #pragma unroll
    for (int kk = 0; kk < 2; ++kk) rdk[kk] = (((kk * 4 + lg) ^ (lr & 7)) * 8);
    const int lr64 = lr * 64;
    int prk[2];
    #pragma unroll
    for (int kk = 0; kk < 2; ++kk) prk[kk] = lr64 + (((kk * 4 + lg) ^ psw) * 8);

    bf16x8 onesf;
    #pragma unroll
    for (int j = 0; j < 8; ++j) onesf[j] = (short)0x3F80;   // bf16 1.0

    #pragma unroll
    for (int phalf = 0; phalf < 2; ++phalf) {
        const int qb = phalf ? (15 - pairi) : pairi;        // 128-row q-tile index
        const ushort* Qbase = Qh + ((size_t)((b * HQ + h) * T_SEQ + qb * 128 + wave * 16 + lr)) * HD;
        bf16x8 qf[2];
        qf[0] = *(const bf16x8*)(Qbase + lg * 8);
        qf[1] = *(const bf16x8*)(Qbase + 32 + lg * 8);

        f32x4 oacc[4];
        #pragma unroll
        for (int dt = 0; dt < 4; ++dt) { oacc[dt][0]=0.f; oacc[dt][1]=0.f; oacc[dt][2]=0.f; oacc[dt][3]=0.f; }
        float l_r[4];
        #pragma unroll
        for (int r = 0; r < 4; ++r) l_r[r] = 0.f;
        float m_run = -INFINITY;

        const int q0w = qb * 128 + wave * 16;               // wave's first q row
        const int q_glob = q0w + lr;
        const int nkt = 2 * qb + 2;

        // strength-reduced staging pointers
        const ushort* kp = Kbase + (size_t)srow * HD + scol;
        const ushort* vp = Vbase + (size_t)srow * T_SEQ + scol;
        u16x8 rK = *(const u16x8*)kp;
        u16x8 rV = *(const u16x8*)vp;
        kp += 64 * HD; vp += 64;
        __syncthreads();   // previous phalf's compute fully done before first ds_write

        for (int kt = 0; kt < nkt; ++kt) {
            const int t0 = kt * 64;
            const int buf = kt & 1;
            *(u16x8*)(buf ? kw1 : kw0) = rK;
            *(u16x8*)(buf ? vw1 : vw0) = rV;
            if (kt + 1 < nkt) {
                rK = *(const u16x8*)kp;
                rV = *(const u16x8*)vp;
                kp += 64 * HD; vp += 64;
            }
            __syncthreads();

            // skip tiles entirely in this wave's future (fully masked)
            if (t0 <= q0w + 15) {
                const ushort* ksb = buf ? &Ks[1][0] : &Ks[0][0];
                const ushort* vsb = buf ? &Vs[1][0] : &Vs[0][0];

                // S^T = K Q^T : sacc[ct][r] = S[k=t0+ct*16+lg*4+r][q=lr]
                f32x4 sacc[4];
                #pragma unroll
                for (int ct = 0; ct < 4; ++ct) { sacc[ct][0]=0.f; sacc[ct][1]=0.f; sacc[ct][2]=0.f; sacc[ct][3]=0.f; }
                __builtin_amdgcn_s_setprio(1);
                #pragma unroll
                for (int kk = 0; kk < 2; ++kk) {
                    #pragma unroll
                    for (int ct = 0; ct < 4; ++ct) {
                        bf16x8 kf = *(const bf16x8*)&ksb[(ct * 16 + lr) * 64 + rdk[kk]];
                        sacc[ct] = __builtin_amdgcn_mfma_f32_16x16x32_bf16(kf, qf[kk], sacc[ct], 0, 0, 0);
                    }
                }
                __builtin_amdgcn_s_setprio(0);

                // causal mask on diagonal-crossing tiles only
                if (t0 + 63 > q0w) {
                    #pragma unroll
                    for (int ct = 0; ct < 4; ++ct) {
                        #pragma unroll
                        for (int r = 0; r < 4; ++r) {
                            int k_glob = t0 + ct * 16 + lg * 4 + r;
                            if (k_glob > q_glob) sacc[ct][r] = -INFINITY;
                        }
                    }
                }

                // per-q-row tile max: 15 local fmax + 2 shfls
                float pm = sacc[0][0];
                #pragma unroll
                for (int ct = 0; ct < 4; ++ct)
                    #pragma unroll
                    for (int r = 0; r < 4; ++r) pm = fmaxf(pm, sacc[ct][r]);
                pm = fmaxf(pm, __shfl_xor(pm, 16));
                pm = fmaxf(pm, __shfl_xor(pm, 32));

                // defer-max rescale (T13)
                bool cskip = (pm <= m_run + 64.f);
                if (!__all(cskip)) {
                    float mn = fmaxf(m_run, pm);
                    float al = exp2f(CEXP * (m_run - mn));
                    m_run = mn;
                    #pragma unroll
                    for (int r = 0; r < 4; ++r) {
                        float alq = __shfl(al, lg * 4 + r);
                        l_r[r] *= alq;
                        #pragma unroll
                        for (int dt = 0; dt < 4; ++dt) oacc[dt][r] *= alq;
                    }
                }

                // P = exp2(C*s - C*m), packed, 4x ds_write_b64
                const float cm = CEXP * m_run;
                #pragma unroll
                for (int ct = 0; ct < 4; ++ct) {
                    float p0 = exp2f(fmaf(CEXP, sacc[ct][0], -cm));
                    float p1 = exp2f(fmaf(CEXP, sacc[ct][1], -cm));
                    float p2 = exp2f(fmaf(CEXP, sacc[ct][2], -cm));
                    float p3 = exp2f(fmaf(CEXP, sacc[ct][3], -cm));
                    uint2 w; w.x = pack2bf(p0, p1); w.y = pack2bf(p2, p3);
                    *(uint2*)&Ps[wave][lr64 + (((ct * 2 + (lg >> 1)) ^ psw) * 8) + (lg & 1) * 4] = w;
                }

                // O += P V ; row sums via ones-MFMA
                f32x4 lacc;
                lacc[0]=0.f; lacc[1]=0.f; lacc[2]=0.f; lacc[3]=0.f;
                __builtin_amdgcn_s_setprio(1);
                #pragma unroll
                for (int kk = 0; kk < 2; ++kk) {
                    bf16x8 pf = *(const bf16x8*)&Ps[wave][prk[kk]];
                    lacc = __builtin_amdgcn_mfma_f32_16x16x32_bf16(pf, onesf, lacc, 0, 0, 0);
                    #pragma unroll
                    for (int dt = 0; dt < 4; ++dt) {
                        bf16x8 vf = *(const bf16x8*)&vsb[(dt * 16 + lr) * 64 + rdk[kk]];
                        oacc[dt] = __builtin_amdgcn_mfma_f32_16x16x32_bf16(pf, vf, oacc[dt], 0, 0, 0);
                    }
                }
                __builtin_amdgcn_s_setprio(0);
                #pragma unroll
                for (int r = 0; r < 4; ++r) l_r[r] += lacc[r];
            }
        }

        // normalize (rcp+mul) + write attOut (bf16, [b*T+t, h*64+d])
        float linv[4];
        #pragma unroll
        for (int r = 0; r < 4; ++r) linv[r] = 1.0f / l_r[r];
        #pragma unroll
        for (int dt = 0; dt < 4; ++dt)
            #pragma unroll
            for (int r = 0; r < 4; ++r) {
                int t = qb * 128 + wave * 16 + lg * 4 + r;
                int d = dt * 16 + lr;
                float v = oacc[dt][r] * linv[r];
                O[((size_t)(b * T_SEQ + t)) * CDIM + h * HD + d] = f2bf(v);
            }
    }
}

extern "C" void kernel_launch(void* const* d_in, const int* in_sizes, int n_in,
                              void* d_out, int out_size, void* d_ws, size_t ws_size,
                              hipStream_t stream) {
    const float* x  = (const float*)d_in[0];
    const float* Wq = (const float*)d_in[1];
    const float* Wk = (const float*)d_in[2];
    const float* Wv = (const float*)d_in[3];
    const float* Wo = (const float*)d_in[4];
    float* out = (float*)d_out;

    ushort* xb    = (ushort*)d_ws;                 //  8,388,608  (x bf16)  [reused as attOut]
    ushort* wqkvb = xb    + 8388608;               //  6,291,456
    ushort* wob   = wqkvb + 6291456;               //  4,194,304
    ushort* qkv   = wob   + 4194304;               // 12,582,912
    ushort* Qh    = qkv   + 12582912;              //  8,388,608
    ushort* Kh    = Qh    + 8388608;               //  2,097,152
    ushort* Vt    = Kh    + 2097152;               //  2,097,152
    ushort* attO  = xb;

    // 1) fused converts
    cvt5_kernel<<<9216, 256, 0, stream>>>(x, Wq, Wk, Wv, Wo, xb, wqkvb, wob);

    // 2) fused QKV projection
    gemm_bt<false><<<dim3(32, 24), 256, 0, stream>>>(xb, wqkvb, qkv, 4096, 3072, 2048);

    // 3) RoPE + rearrange
    rope_qk<<<20480, 256, 0, stream>>>(qkv, Qh, Kh);
    v_transpose<<<dim3(16, 32), 256, 0, stream>>>(qkv, Vt);

    // 4) attention (8-wave QBLK=128, triangle-paired)
    attn_kernel<<<dim3(8, 32, 2), 512, 0, stream>>>(Qh, Kh, Vt, attO);

    // 5) output projection
    gemm_bt<true><<<dim3(32, 16), 256, 0, stream>>>(attO, wob, out, 4096, 2048, 2048);
}